// Round 10
// baseline (164.231 us; speedup 1.0000x reference)
//
#include <hip/hip_runtime.h>

#define NN 4096
#define NE 8192
#define NLG 32768
#define CAP 32

typedef unsigned int u32;
typedef unsigned short u16;
typedef __attribute__((ext_vector_type(4))) float f32x4;
typedef __attribute__((ext_vector_type(8))) short bf16x8;
typedef __attribute__((ext_vector_type(8))) unsigned short u16x8;
typedef __attribute__((ext_vector_type(4))) unsigned short u16x4;

__device__ __forceinline__ float bf2f(u16 u) { return __uint_as_float(((u32)u) << 16); }
__device__ __forceinline__ u16 f2bf(float f) {
    u32 x = __float_as_uint(f);
    return (u16)((x + 0x7fffu + ((x >> 16) & 1u)) >> 16);  // RNE
}

// ================= K1: prep (converts/transposes/bias) + bucket append, fused =================
struct PAArgs {
    const float *x, *ex;
    const float *nW0, *nW1, *eWl0, *eWu0, *eWl1, *eWu1, *fnW, *feW, *nb0, *nb1;
    const int *nei, *eil, *eiu;
    u32 *cntA, *cntL, *cntU;            // raw counters (zeroed by memset)
    u32 *colA, *colL, *colU, *eidL, *eidU;
    u16 *Zb1n, *Zb1e, *nW0T, *nW1T, *eW1T, *eW2T, *fnWT, *feWT;
    float *nb0s, *nb1s;
};

// 4-wide transpose: thread reads 16B coalesced (4 consecutive nn of src row kk),
// writes 4 elems down dst's contiguous-fast kk dim (L2-absorbed scatter).
__device__ __forceinline__ void wtrK4(const float* src, u16* dst, u32 i, int Kp, int Nw, int ld, int kofs) {
    int n4 = i / Kp, kk = i - n4 * Kp, nn = n4 * 4;
    f32x4 v = *(const f32x4*)(src + (size_t)kk * Nw + nn);
#pragma unroll
    for (int e = 0; e < 4; ++e) dst[(size_t)(nn + e) * ld + kofs + kk] = f2bf(v[e]);
}
__device__ __forceinline__ void wtrS4(const float* sa, const float* sb, u16* dst, u32 i, int Kp, int Nw, int ld) {
    int n4 = i / Kp, kk = i - n4 * Kp, nn = n4 * 4;
    f32x4 va = *(const f32x4*)(sa + (size_t)kk * Nw + nn);
    f32x4 vb = *(const f32x4*)(sb + (size_t)kk * Nw + nn);
#pragma unroll
    for (int e = 0; e < 4; ++e) dst[(size_t)(nn + e) * ld + kk] = f2bf(va[e] + vb[e]);
}

__global__ __launch_bounds__(256) void prep_append(PAArgs A) {
    const u32 gid = blockIdx.x * blockDim.x + threadIdx.x;
    const u32 gsz = gridDim.x * blockDim.x;
    const u32 C0 = 32768;                 // x conv (8-col items)
    const u32 C1 = C0 + 32768;            // ex conv (8-col items)
    const u32 C2 = C1 + 6144;             // nW0T (Kp=192, /4)
    const u32 C3 = C2 + 12288;            // nW1T (Kp=384, /4)
    const u32 C4 = C3 + 1024;             // eW1T sum block (Kp=32, /4)
    const u32 C5 = C4 + 1024;             // eWl0 k=1
    const u32 C6 = C5 + 1024;             // eWl0 k=2
    const u32 C7 = C6 + 1024;             // eWu0 k=1
    const u32 C8 = C7 + 1024;             // eWu0 k=2
    const u32 C9 = C8 + 4096;             // eW2T sum block (Kp=128, /4)
    const u32 C10 = C9 + 4096;            // eWl1 k=1
    const u32 C11 = C10 + 4096;           // eWl1 k=2
    const u32 C12 = C11 + 4096;           // eWu1 k=1
    const u32 C13 = C12 + 4096;           // eWu1 k=2
    const u32 C14 = C13 + 2048;           // fnWT
    const u32 C15 = C14 + 2048;           // feWT
    const u32 C16 = C15 + 256;            // bias sums
    const u32 C17 = C16 + (NE + 2 * NLG); // append
    for (u32 i = gid; i < C17; i += gsz) {
        if (i < C0) {
            u32 t = i; int r = t >> 3, c8 = t & 7;
            f32x4 v0 = *(const f32x4*)(A.x + (size_t)t * 8);
            f32x4 v1 = *(const f32x4*)(A.x + (size_t)t * 8 + 4);
            u16x8 o;
#pragma unroll
            for (int e = 0; e < 4; ++e) { o[e] = f2bf(v0[e]); o[4 + e] = f2bf(v1[e]); }
            *(u16x8*)(A.Zb1n + (size_t)r * 192 + c8 * 8) = o;
        } else if (i < C1) {
            u32 t = i - C0; int r = t >> 2, c8 = t & 3;
            f32x4 v0 = *(const f32x4*)(A.ex + (size_t)t * 8);
            f32x4 v1 = *(const f32x4*)(A.ex + (size_t)t * 8 + 4);
            u16x8 o;
#pragma unroll
            for (int e = 0; e < 4; ++e) { o[e] = f2bf(v0[e]); o[4 + e] = f2bf(v1[e]); }
            *(u16x8*)(A.Zb1e + (size_t)r * 160 + c8 * 8) = o;
        }
        else if (i < C2)  wtrK4(A.nW0, A.nW0T, i - C1, 192, 128, 192, 0);
        else if (i < C3)  wtrK4(A.nW1, A.nW1T, i - C2, 384, 128, 384, 0);
        else if (i < C4)  wtrS4(A.eWl0, A.eWu0, A.eW1T, i - C3, 32, 128, 160);
        else if (i < C5)  wtrK4(A.eWl0 + 32 * 128,     A.eW1T, i - C4, 32, 128, 160, 32);
        else if (i < C6)  wtrK4(A.eWl0 + 2 * 32 * 128, A.eW1T, i - C5, 32, 128, 160, 64);
        else if (i < C7)  wtrK4(A.eWu0 + 32 * 128,     A.eW1T, i - C6, 32, 128, 160, 96);
        else if (i < C8)  wtrK4(A.eWu0 + 2 * 32 * 128, A.eW1T, i - C7, 32, 128, 160, 128);
        else if (i < C9)  wtrS4(A.eWl1, A.eWu1, A.eW2T, i - C8, 128, 128, 640);
        else if (i < C10) wtrK4(A.eWl1 + 128 * 128,     A.eW2T, i - C9, 128, 128, 640, 128);
        else if (i < C11) wtrK4(A.eWl1 + 2 * 128 * 128, A.eW2T, i - C10, 128, 128, 640, 256);
        else if (i < C12) wtrK4(A.eWu1 + 128 * 128,     A.eW2T, i - C11, 128, 128, 640, 384);
        else if (i < C13) wtrK4(A.eWu1 + 2 * 128 * 128, A.eW2T, i - C12, 128, 128, 640, 512);
        else if (i < C14) wtrK4(A.fnW, A.fnWT, i - C13, 128, 64, 128, 0);
        else if (i < C15) wtrK4(A.feW, A.feWT, i - C14, 128, 64, 128, 0);
        else if (i < C16) {
            u32 t = i - C15;
            if (t < 128) { float s = 0.f; for (int k = 0; k < 3; ++k) s += A.nb0[k * 128 + t]; A.nb0s[t] = s; }
            else { t -= 128; float s = 0.f; for (int k = 0; k < 3; ++k) s += A.nb1[k * 128 + t]; A.nb1s[t] = s; }
        } else {
            u32 t = i - C16;
            if (t < NE) {
                int r = A.nei[t];
                u32 p = atomicAdd(&A.cntA[r], 1u);
                if (p < CAP) A.colA[r * CAP + p] = (u32)A.nei[NE + t];
            } else if (t < NE + NLG) {
                u32 e = t - NE;
                int r = A.eil[e];
                u32 p = atomicAdd(&A.cntL[r], 1u);
                if (p < CAP) { A.colL[r * CAP + p] = (u32)A.eil[NLG + e]; A.eidL[r * CAP + p] = e; }
            } else {
                u32 e = t - NE - NLG;
                int r = A.eiu[e];
                u32 p = atomicAdd(&A.cntU[r], 1u);
                if (p < CAP) { A.colU[r * CAP + p] = (u32)A.eiu[NLG + e]; A.eidU[r * CAP + p] = e; }
            }
        }
    }
}

// ================= K2: fused resolve + layer-1 hop-1 spmm =================
// Uniform 32-row blocks: A 128 + L 256 + U 256 = 640 blocks, 8 slot-threads/row.
// In-place semantics: loser/dup slots get w=0. A: first-slot-wins. L/U: max-eid-wins.
struct RHArgs {
    const u32 *cntA, *cntL, *cntU;
    const u32 *colA, *colL, *colU, *eidL, *eidU;
    const float *eal, *eau;
    uint2 *rb1A, *rb1L, *rb1U;
    u16 *Zb1n, *Zb1e;
};

__global__ __launch_bounds__(256) void resolve_hop1(RHArgs A) {
    __shared__ uint2 bkt[32][33];   // +1 pad: breaks 256B-stride bank aliasing
    __shared__ u32 jns[32];
    const int b = blockIdx.x, tid = threadIdx.x;
    const int seg = (b < 128) ? 0 : (b < 384 ? 1 : 2);   // A / L / U
    const int rowbase = (seg == 0 ? b : (seg == 1 ? b - 128 : b - 384)) * 32;
    const u32* cnt = seg == 0 ? A.cntA : (seg == 1 ? A.cntL : A.cntU);
    const u32* col = seg == 0 ? A.colA : (seg == 1 ? A.colL : A.colU);
    uint2* rb = seg == 0 ? A.rb1A : (seg == 1 ? A.rb1L : A.rb1U);

    // ---- phase A: resolve into LDS + global rb1 (8 slot-threads/row) ----
    {
        const int lr = tid >> 3, s = tid & 7;
        const int row = rowbase + lr;
        u32 jn = cnt[row]; if (jn > CAP) jn = CAP;
        if (s == 0) jns[lr] = jn;
        const u32* cp = col + row * CAP;
        if (seg == 0) {
            for (u32 j = s; j < jn; j += 8) {
                u32 cj = cp[j];
                float w = 1.0f;
                for (u32 j2 = 0; j2 < j; ++j2) if (cp[j2] == cj) { w = 0.0f; break; }
                uint2 v = make_uint2(cj, __float_as_uint(w));
                bkt[lr][j] = v; rb[row * CAP + j] = v;
            }
        } else {
            const u32* ep = (seg == 1 ? A.eidL : A.eidU) + row * CAP;
            const float* wsr = seg == 1 ? A.eal : A.eau;
            for (u32 j = s; j < jn; j += 8) {
                u32 cj = cp[j], ej = ep[j];
                float w = wsr[ej];
                for (u32 j2 = 0; j2 < jn; ++j2)
                    if (j2 != j && cp[j2] == cj && ep[j2] > ej) { w = 0.0f; break; }
                uint2 v = make_uint2(cj, __float_as_uint(w));
                bkt[lr][j] = v; rb[row * CAP + j] = v;
            }
        }
    }
    __syncthreads();

    // ---- phase B: hop-1 gather using LDS buckets (8 col-groups/row) ----
    const int lr2 = tid >> 3, g = tid & 7;
    const int row2 = rowbase + lr2;
    const u32 jn2 = jns[lr2];
    if (seg == 0) {
        // node: 64 cols = 8 groups x 8
        const u16* srcg = A.Zb1n + g * 8;
        float acc[8] = {};
        for (u32 j = 0; j < jn2; ++j) {
            uint2 q = bkt[lr2][j];
            u16x8 xv = *(const u16x8*)(srcg + (size_t)q.x * 192);
            float w = __uint_as_float(q.y);
#pragma unroll
            for (int e = 0; e < 8; ++e) acc[e] = fmaf(w, bf2f(xv[e]), acc[e]);
        }
        u16x8 o;
#pragma unroll
        for (int e = 0; e < 8; ++e) o[e] = f2bf(acc[e]);
        *(u16x8*)(A.Zb1n + 64 + (size_t)row2 * 192 + g * 8) = o;
    } else {
        // edge: 32 cols = 8 groups x 4
        const u16* srcg = A.Zb1e + g * 4;
        u16* dst = seg == 1 ? A.Zb1e + 32 : A.Zb1e + 96;
        float acc[4] = {};
        for (u32 j = 0; j < jn2; ++j) {
            uint2 q = bkt[lr2][j];
            u16x4 xv = *(const u16x4*)(srcg + (size_t)q.x * 160);
            float w = __uint_as_float(q.y);
#pragma unroll
            for (int e = 0; e < 4; ++e) acc[e] = fmaf(w, bf2f(xv[e]), acc[e]);
        }
        u16x4 o;
#pragma unroll
        for (int e = 0; e < 4; ++e) o[e] = f2bf(acc[e]);
        *(u16x4*)(dst + (size_t)row2 * 160 + g * 4) = o;
    }
}

// ================= layer-2 hop-1 spmm: 8 threads/row, dual 8-col slices =================
struct RSeg { const u32* cnt; const uint2* rb; const u16* src; u16* dst; int n; int ld; };
struct Seg3 { RSeg s[3]; };

__device__ __forceinline__ void spmm_row16(const RSeg& s, int t) {
    int row = t >> 3, g = t & 7;
    u32 jn = s.cnt[row]; if (jn > CAP) jn = CAP;
    const uint2* bp = s.rb + (size_t)row * CAP;
    const u16* s0 = s.src + g * 8;
    const u16* s1 = s.src + g * 8 + 64;
    float acc[16] = {};
    u32 j = 0;
    for (; j + 2 <= jn; j += 2) {
        uint2 q0 = bp[j], q1 = bp[j + 1];
        u16x8 a0 = *(const u16x8*)(s0 + (size_t)q0.x * s.ld);
        u16x8 b0 = *(const u16x8*)(s1 + (size_t)q0.x * s.ld);
        u16x8 a1 = *(const u16x8*)(s0 + (size_t)q1.x * s.ld);
        u16x8 b1 = *(const u16x8*)(s1 + (size_t)q1.x * s.ld);
        float w0 = __uint_as_float(q0.y), w1 = __uint_as_float(q1.y);
#pragma unroll
        for (int e = 0; e < 8; ++e) {
            acc[e]     = fmaf(w0, bf2f(a0[e]), acc[e]);
            acc[8 + e] = fmaf(w0, bf2f(b0[e]), acc[8 + e]);
            acc[e]     = fmaf(w1, bf2f(a1[e]), acc[e]);
            acc[8 + e] = fmaf(w1, bf2f(b1[e]), acc[8 + e]);
        }
    }
    for (; j < jn; ++j) {
        uint2 q = bp[j];
        u16x8 a0 = *(const u16x8*)(s0 + (size_t)q.x * s.ld);
        u16x8 b0 = *(const u16x8*)(s1 + (size_t)q.x * s.ld);
        float w = __uint_as_float(q.y);
#pragma unroll
        for (int e = 0; e < 8; ++e) {
            acc[e]     = fmaf(w, bf2f(a0[e]), acc[e]);
            acc[8 + e] = fmaf(w, bf2f(b0[e]), acc[8 + e]);
        }
    }
    u16x8 o0, o1;
#pragma unroll
    for (int e = 0; e < 8; ++e) { o0[e] = f2bf(acc[e]); o1[e] = f2bf(acc[8 + e]); }
    *(u16x8*)(s.dst + (size_t)row * s.ld + g * 8) = o0;
    *(u16x8*)(s.dst + (size_t)row * s.ld + g * 8 + 64) = o1;
}

__global__ __launch_bounds__(256) void spmm16_kernel(Seg3 P) {
    int id = blockIdx.x * blockDim.x + threadIdx.x;
    int base = 0;
#pragma unroll
    for (int i = 0; i < 3; ++i) {
        int n = P.s[i].n;
        if (id < base + n) { spmm_row16(P.s[i], id - base); return; }
        base += n;
    }
}

// ================= K4: layer-1 GEMM with fused hop-2 =================
// 1 tile/block (grid 768, striped node/edge), 4 waves x 32 N-cols.
// 256 threads stage hop-2 (16 thr/row, u16x4 slices); barrier AFTER global-K MFMA.
// node A-tile: k[0,128) global (x|hop1), k[128,192) LDS (hop2)
// edge A-tile: k[0,64) g, k[64,96) LDS(L2), k[96,128) g, k[128,160) LDS(U2)
struct G1Args {
    const u16 *Zb1n, *Zb1e, *nW0T, *eW1T;
    const float *nb0s, *eb0;
    const u32 *cntA, *cntL, *cntU;
    const uint2 *rb1A, *rb1L, *rb1U;
    u16 *Zb2n, *Zb2e;
};

__global__ __launch_bounds__(256) void gemm1_kernel(G1Args A) {
    __shared__ u16 h2[16][72];   // stride 72: fragment reads land 2-way (free)
    const int tid = threadIdx.x;
    const int wv = tid >> 6, lane = tid & 63;
    const int bid = blockIdx.x;
    const int s = (bid % 3) * 256 + bid / 3;   // stripe: mix node/edge through launch order
    const bool node = s < 256;
    const int m0 = (node ? s : s - 256) * 16;

    // ---- stage hop2 (256 threads, 16 thr/row, 4-col slices) ----
    // node: 64 cols (16 x 4). edge: L2 32 cols (g 0..7), U2 32 cols (g 8..15).
    {
        const int lr = tid >> 4, g = tid & 15;
        const u32* cnt; const uint2* rb; const u16* src; int ld, dc;
        if (node) { cnt = A.cntA; rb = A.rb1A; src = A.Zb1n + 64 + g * 4; ld = 192; dc = g * 4; }
        else {
            const bool isL = g < 8; const int gg = isL ? g : g - 8;
            cnt = isL ? A.cntL : A.cntU; rb = isL ? A.rb1L : A.rb1U;
            src = (isL ? A.Zb1e + 32 : A.Zb1e + 96) + gg * 4; ld = 160;
            dc = (isL ? 0 : 32) + gg * 4;
        }
        const int row = m0 + lr;
        u32 jn = cnt[row]; if (jn > CAP) jn = CAP;
        const uint2* bp = rb + (size_t)row * CAP;
        float acc[4] = {};
        for (u32 j = 0; j < jn; ++j) {
            uint2 qe = bp[j];
            float w = __uint_as_float(qe.y);
            u16x4 a0 = *(const u16x4*)(src + (size_t)qe.x * ld);
#pragma unroll
            for (int e = 0; e < 4; ++e) acc[e] = fmaf(w, bf2f(a0[e]), acc[e]);
        }
        u16x4 o0;
#pragma unroll
        for (int e = 0; e < 4; ++e) o0[e] = f2bf(acc[e]);
        *(u16x4*)&h2[lr][dc] = o0;
    }

    // ---- MFMA GEMM, split-K; wave = 32 N-cols; barrier after global-K ----
    const int c = lane & 15, koff = (lane >> 4) * 8;
    const int n0 = wv * 32;
    f32x4 acc[2] = {};
    const u16* Lr = &h2[c][koff];
    if (node) {
        const u16* Ap = A.Zb1n + (size_t)(m0 + c) * 192 + koff;
        const u16* Wp = A.nW0T + (size_t)(n0 + c) * 192 + koff;
        const size_t ws = (size_t)16 * 192;
#pragma unroll
        for (int k0 = 0; k0 < 128; k0 += 32) {
            bf16x8 af = *(const bf16x8*)(Ap + k0);
#pragma unroll
            for (int nt = 0; nt < 2; ++nt)
                acc[nt] = __builtin_amdgcn_mfma_f32_16x16x32_bf16(af, *(const bf16x8*)(Wp + nt * ws + k0), acc[nt], 0, 0, 0);
        }
        __syncthreads();
#pragma unroll
        for (int k0 = 128; k0 < 192; k0 += 32) {
            bf16x8 af = *(const bf16x8*)(Lr + (k0 - 128));
#pragma unroll
            for (int nt = 0; nt < 2; ++nt)
                acc[nt] = __builtin_amdgcn_mfma_f32_16x16x32_bf16(af, *(const bf16x8*)(Wp + nt * ws + k0), acc[nt], 0, 0, 0);
        }
        const int orow = m0 + (lane >> 4) * 4;
#pragma unroll
        for (int nt = 0; nt < 2; ++nt) {
            int col = n0 + nt * 16 + c;
            float bv = A.nb0s[col];
#pragma unroll
            for (int r = 0; r < 4; ++r)
                A.Zb2n[(size_t)(orow + r) * 384 + col] = f2bf(fmaxf(acc[nt][r] + bv, 0.f));
        }
    } else {
        const u16* Ap = A.Zb1e + (size_t)(m0 + c) * 160 + koff;
        const u16* Wp = A.eW1T + (size_t)(n0 + c) * 160 + koff;
        const size_t ws = (size_t)16 * 160;
        bf16x8 af;
        af = *(const bf16x8*)(Ap + 0);
#pragma unroll
        for (int nt = 0; nt < 2; ++nt)
            acc[nt] = __builtin_amdgcn_mfma_f32_16x16x32_bf16(af, *(const bf16x8*)(Wp + nt * ws + 0), acc[nt], 0, 0, 0);
        af = *(const bf16x8*)(Ap + 32);
#pragma unroll
        for (int nt = 0; nt < 2; ++nt)
            acc[nt] = __builtin_amdgcn_mfma_f32_16x16x32_bf16(af, *(const bf16x8*)(Wp + nt * ws + 32), acc[nt], 0, 0, 0);
        af = *(const bf16x8*)(Ap + 96);
#pragma unroll
        for (int nt = 0; nt < 2; ++nt)
            acc[nt] = __builtin_amdgcn_mfma_f32_16x16x32_bf16(af, *(const bf16x8*)(Wp + nt * ws + 96), acc[nt], 0, 0, 0);
        __syncthreads();
        af = *(const bf16x8*)(Lr + 0);      // L2 hop2, kabs 64
#pragma unroll
        for (int nt = 0; nt < 2; ++nt)
            acc[nt] = __builtin_amdgcn_mfma_f32_16x16x32_bf16(af, *(const bf16x8*)(Wp + nt * ws + 64), acc[nt], 0, 0, 0);
        af = *(const bf16x8*)(Lr + 32);     // U2 hop2, kabs 128
#pragma unroll
        for (int nt = 0; nt < 2; ++nt)
            acc[nt] = __builtin_amdgcn_mfma_f32_16x16x32_bf16(af, *(const bf16x8*)(Wp + nt * ws + 128), acc[nt], 0, 0, 0);
        const int orow = m0 + (lane >> 4) * 4;
#pragma unroll
        for (int nt = 0; nt < 2; ++nt) {
            int col = n0 + nt * 16 + c;
            float bv = A.eb0[col];
#pragma unroll
            for (int r = 0; r < 4; ++r)
                A.Zb2e[(size_t)(orow + r) * 640 + col] = f2bf(fmaxf(acc[nt][r] + bv, 0.f));
        }
    }
}

// ================= K6: layer-2 GEMM + head with fused hop-2, M=32 tiles =================
// 1 tile (32 rows)/block, grid 384 (striped 1:2 node:edge), 8 waves x 16 N-cols x 2
// row-subtiles: each weight fragment feeds 2 MFMAs (weight L2 traffic halved).
// 512 threads stage hop-2 (16 thr/row; edge loops L/U). Barrier after global-K.
// Head: 8 tasks (2 row-tiles x 4 col-groups) -> all 8 waves busy.
// node: k[0,256) global (h|hop1), k[256,384) LDS
// edge: k[0,256)+k[384,512) global, then LDS(L2 k[256,384)), LDS(U2 k[512,640))
struct G2Args {
    const u16 *Zb2n, *Zb2e, *nW1T, *eW2T, *fnWT, *feWT;
    const float *nb1s, *eb1, *fnb, *feb;
    const u32 *cntA, *cntL, *cntU;
    const uint2 *rb1A, *rb1L, *rb1U;
    float *outn, *oute;
};

__global__ __launch_bounds__(512) void gemm2_head(G2Args A) {
    __shared__ u16 h2[32][264];   // stride 264: fragment reads land 2-way
    __shared__ u16 g2[32][136];   // +8 pad: head reads 2-way instead of 16-way
    const int tid = threadIdx.x;
    const int wv = tid >> 6, lane = tid & 63;
    const int bid = blockIdx.x;
    const int s = (bid % 3) * 128 + bid / 3;   // stripe: 1 node : 2 edge through launch order
    const bool node = s < 128;
    const int m0 = (node ? s : s - 128) * 32;

    // ---- stage hop2 (512 threads, 16 thr/row over 32 rows) ----
    {
        const int lr = tid >> 4, g = tid & 15;
        const int row = m0 + lr;
        if (node) {
            // 128 cols: 16 x 8-col slices
            u32 jn = A.cntA[row]; if (jn > CAP) jn = CAP;
            const uint2* bp = A.rb1A + (size_t)row * CAP;
            const u16* src = A.Zb2n + 128 + g * 8;
            float acc[8] = {};
            for (u32 j = 0; j < jn; ++j) {
                uint2 qe = bp[j];
                float w = __uint_as_float(qe.y);
                u16x8 a0 = *(const u16x8*)(src + (size_t)qe.x * 384);
#pragma unroll
                for (int e = 0; e < 8; ++e) acc[e] = fmaf(w, bf2f(a0[e]), acc[e]);
            }
            u16x8 o0;
#pragma unroll
            for (int e = 0; e < 8; ++e) o0[e] = f2bf(acc[e]);
            *(u16x8*)&h2[lr][g * 8] = o0;
        } else {
            // 256 cols: each thread stages slice g of L2 (dc g*8) AND U2 (dc 128+g*8)
#pragma unroll
            for (int m = 0; m < 2; ++m) {
                const u32* cnt = m == 0 ? A.cntL : A.cntU;
                const uint2* rb = m == 0 ? A.rb1L : A.rb1U;
                const u16* src = (m == 0 ? A.Zb2e + 128 : A.Zb2e + 384) + g * 8;
                u32 jn = cnt[row]; if (jn > CAP) jn = CAP;
                const uint2* bp = rb + (size_t)row * CAP;
                float acc[8] = {};
                for (u32 j = 0; j < jn; ++j) {
                    uint2 qe = bp[j];
                    float w = __uint_as_float(qe.y);
                    u16x8 a0 = *(const u16x8*)(src + (size_t)qe.x * 640);
#pragma unroll
                    for (int e = 0; e < 8; ++e) acc[e] = fmaf(w, bf2f(a0[e]), acc[e]);
                }
                u16x8 o0;
#pragma unroll
                for (int e = 0; e < 8; ++e) o0[e] = f2bf(acc[e]);
                *(u16x8*)&h2[lr][m * 128 + g * 8] = o0;
            }
        }
    }

    // ---- layer-2 GEMM: wave wv = 16 N-cols x 2 row-subtiles; barrier after global-K ----
    const int c = lane & 15, q = lane >> 4, koff = q * 8;
    f32x4 acc[2] = {};
    const u16* Lr0 = &h2[c][koff];
    const u16* Lr1 = &h2[16 + c][koff];
    const u16* hWT; const float *hB; float* outp;
    if (node) {
        hWT = A.fnWT; hB = A.fnb; outp = A.outn;
        const u16* Ap0 = A.Zb2n + (size_t)(m0 + c) * 384 + koff;
        const u16* Ap1 = A.Zb2n + (size_t)(m0 + 16 + c) * 384 + koff;
        const u16* Wp = A.nW1T + (size_t)(wv * 16 + c) * 384 + koff;
#pragma unroll
        for (int k0 = 0; k0 < 256; k0 += 32) {
            bf16x8 wf = *(const bf16x8*)(Wp + k0);
            acc[0] = __builtin_amdgcn_mfma_f32_16x16x32_bf16(*(const bf16x8*)(Ap0 + k0), wf, acc[0], 0, 0, 0);
            acc[1] = __builtin_amdgcn_mfma_f32_16x16x32_bf16(*(const bf16x8*)(Ap1 + k0), wf, acc[1], 0, 0, 0);
        }
        __syncthreads();
#pragma unroll
        for (int k0 = 256; k0 < 384; k0 += 32) {
            bf16x8 wf = *(const bf16x8*)(Wp + k0);
            acc[0] = __builtin_amdgcn_mfma_f32_16x16x32_bf16(*(const bf16x8*)(Lr0 + (k0 - 256)), wf, acc[0], 0, 0, 0);
            acc[1] = __builtin_amdgcn_mfma_f32_16x16x32_bf16(*(const bf16x8*)(Lr1 + (k0 - 256)), wf, acc[1], 0, 0, 0);
        }
        {
            int col = wv * 16 + c;
            float bv = A.nb1s[col];
#pragma unroll
            for (int rt = 0; rt < 2; ++rt)
#pragma unroll
                for (int r = 0; r < 4; ++r)
                    g2[rt * 16 + q * 4 + r][col] = f2bf(fmaxf(acc[rt][r] + bv, 0.f));
        }
    } else {
        hWT = A.feWT; hB = A.feb; outp = A.oute;
        const u16* Ap0 = A.Zb2e + (size_t)(m0 + c) * 640 + koff;
        const u16* Ap1 = A.Zb2e + (size_t)(m0 + 16 + c) * 640 + koff;
        const u16* Wp = A.eW2T + (size_t)(wv * 16 + c) * 640 + koff;
#pragma unroll
        for (int k0 = 0; k0 < 256; k0 += 32) {
            bf16x8 wf = *(const bf16x8*)(Wp + k0);
            acc[0] = __builtin_amdgcn_mfma_f32_16x16x32_bf16(*(const bf16x8*)(Ap0 + k0), wf, acc[0], 0, 0, 0);
            acc[1] = __builtin_amdgcn_mfma_f32_16x16x32_bf16(*(const bf16x8*)(Ap1 + k0), wf, acc[1], 0, 0, 0);
        }
#pragma unroll
        for (int k0 = 384; k0 < 512; k0 += 32) {
            bf16x8 wf = *(const bf16x8*)(Wp + k0);
            acc[0] = __builtin_amdgcn_mfma_f32_16x16x32_bf16(*(const bf16x8*)(Ap0 + k0), wf, acc[0], 0, 0, 0);
            acc[1] = __builtin_amdgcn_mfma_f32_16x16x32_bf16(*(const bf16x8*)(Ap1 + k0), wf, acc[1], 0, 0, 0);
        }
        __syncthreads();
#pragma unroll
        for (int k0 = 256; k0 < 384; k0 += 32) {
            bf16x8 wf = *(const bf16x8*)(Wp + k0);
            acc[0] = __builtin_amdgcn_mfma_f32_16x16x32_bf16(*(const bf16x8*)(Lr0 + (k0 - 256)), wf, acc[0], 0, 0, 0);
            acc[1] = __builtin_amdgcn_mfma_f32_16x16x32_bf16(*(const bf16x8*)(Lr1 + (k0 - 256)), wf, acc[1], 0, 0, 0);
        }
#pragma unroll
        for (int k0 = 512; k0 < 640; k0 += 32) {
            bf16x8 wf = *(const bf16x8*)(Wp + k0);
            acc[0] = __builtin_amdgcn_mfma_f32_16x16x32_bf16(*(const bf16x8*)(Lr0 + (128 + k0 - 512)), wf, acc[0], 0, 0, 0);
            acc[1] = __builtin_amdgcn_mfma_f32_16x16x32_bf16(*(const bf16x8*)(Lr1 + (128 + k0 - 512)), wf, acc[1], 0, 0, 0);
        }
        {
            int col = wv * 16 + c;
            float bv = A.eb1[col];
#pragma unroll
            for (int rt = 0; rt < 2; ++rt)
#pragma unroll
                for (int r = 0; r < 4; ++r)
                    g2[rt * 16 + q * 4 + r][col] = f2bf(fmaxf(acc[rt][r] + bv, 0.f));
        }
    }
    __syncthreads();

    // ---- head: 8 waves = 2 row-tiles x 4 col-groups ----
    {
        const int rt = wv >> 2, cg = wv & 3;
        f32x4 hacc = {};
        const u16* Hp = hWT + (size_t)(cg * 16 + c) * 128 + koff;
#pragma unroll
        for (int k0 = 0; k0 < 128; k0 += 32) {
            bf16x8 af = *(const bf16x8*)(&g2[rt * 16 + c][koff + k0]);
            bf16x8 bf = *(const bf16x8*)(Hp + k0);
            hacc = __builtin_amdgcn_mfma_f32_16x16x32_bf16(af, bf, hacc, 0, 0, 0);
        }
        int col = cg * 16 + c;
        float bv = hB[col];
#pragma unroll
        for (int r = 0; r < 4; ++r)
            outp[(size_t)(m0 + rt * 16 + q * 4 + r) * 64 + col] = hacc[r] + bv;
    }
}

// ================= launch =================
extern "C" void kernel_launch(void* const* d_in, const int* in_sizes, int n_in,
                              void* d_out, int out_size, void* d_ws, size_t ws_size,
                              hipStream_t stream)
{
    const float* x    = (const float*)d_in[0];
    const float* ex   = (const float*)d_in[1];
    const int*   nei  = (const int*)d_in[2];
    const int*   eil  = (const int*)d_in[3];
    const float* eal  = (const float*)d_in[4];
    const int*   eiu  = (const int*)d_in[5];
    const float* eau  = (const float*)d_in[6];
    const float* nW0  = (const float*)d_in[7];
    const float* nb0  = (const float*)d_in[8];
    const float* nW1  = (const float*)d_in[9];
    const float* nb1  = (const float*)d_in[10];
    const float* fnW  = (const float*)d_in[11];
    const float* fnb  = (const float*)d_in[12];
    const float* eWl0 = (const float*)d_in[13];
    const float* eWu0 = (const float*)d_in[14];
    const float* eb0  = (const float*)d_in[15];
    const float* eWl1 = (const float*)d_in[16];
    const float* eWu1 = (const float*)d_in[17];
    const float* eb1  = (const float*)d_in[18];
    const float* feW  = (const float*)d_in[19];
    const float* feb  = (const float*)d_in[20];

    char* wsb = (char*)d_ws;
    size_t off = 0;
    auto alloc = [&](size_t bytes) { void* p = wsb + off; off += (bytes + 255) & ~(size_t)255; return p; };

    // ---- zeroed region (single small memset): raw append counters only ----
    u32* cntA = (u32*)alloc(NN * 4);
    u32* cntL = (u32*)alloc(NE * 4);
    u32* cntU = (u32*)alloc(NE * 4);
    size_t zbytes = off;   // ~82 KB

    uint2* rb1A = (uint2*)alloc((size_t)NN * CAP * 8);
    uint2* rb1L = (uint2*)alloc((size_t)NE * CAP * 8);
    uint2* rb1U = (uint2*)alloc((size_t)NE * CAP * 8);

    u32* colA = (u32*)alloc((size_t)NN * CAP * 4);
    u32* colL = (u32*)alloc((size_t)NE * CAP * 4);
    u32* colU = (u32*)alloc((size_t)NE * CAP * 4);
    u32* eidL = (u32*)alloc((size_t)NE * CAP * 4);
    u32* eidU = (u32*)alloc((size_t)NE * CAP * 4);

    u16* Zb1n = (u16*)alloc((size_t)4096 * 192 * 2);
    u16* Zb1e = (u16*)alloc((size_t)8192 * 160 * 2);
    u16* Zb2n = (u16*)alloc((size_t)4096 * 384 * 2);
    u16* Zb2e = (u16*)alloc((size_t)8192 * 640 * 2);

    u16* nW0T = (u16*)alloc((size_t)128 * 192 * 2);
    u16* nW1T = (u16*)alloc((size_t)128 * 384 * 2);
    u16* eW1T = (u16*)alloc((size_t)128 * 160 * 2);
    u16* eW2T = (u16*)alloc((size_t)128 * 640 * 2);
    u16* fnWT = (u16*)alloc((size_t)64 * 128 * 2);
    u16* feWT = (u16*)alloc((size_t)64 * 128 * 2);
    float* nb0s = (float*)alloc(128 * 4);
    float* nb1s = (float*)alloc(128 * 4);

    // ---- D0: zero counters (~82 KB) ----
    hipMemsetAsync(d_ws, 0, zbytes, stream);

    // ---- D1: prep + append ----
    PAArgs PA{x, ex, nW0, nW1, eWl0, eWu0, eWl1, eWu1, fnW, feW, nb0, nb1,
              nei, eil, eiu,
              cntA, cntL, cntU, colA, colL, colU, eidL, eidU,
              Zb1n, Zb1e, nW0T, nW1T, eW1T, eW2T, fnWT, feWT, nb0s, nb1s};
    prep_append<<<dim3(736), dim3(256), 0, stream>>>(PA);

    // ---- D2: fused resolve + layer-1 hop-1 (640 x 32-row blocks) ----
    RHArgs RH{cntA, cntL, cntU, colA, colL, colU, eidL, eidU, eal, eau,
              rb1A, rb1L, rb1U, Zb1n, Zb1e};
    resolve_hop1<<<dim3(640), dim3(256), 0, stream>>>(RH);

    // ---- D3: layer-1 GEMMs with fused hop-2 (striped tiles, 4 waves) ----
    {
        G1Args G1{Zb1n, Zb1e, nW0T, eW1T, nb0s, eb0,
                  cntA, cntL, cntU, rb1A, rb1L, rb1U, Zb2n, Zb2e};
        gemm1_kernel<<<dim3(768), dim3(256), 0, stream>>>(G1);
    }

    // ---- D4: layer-2 hop-1 (8 thr/row, dual slices) ----
    {
        Seg3 P;
        P.s[0] = RSeg{cntA, rb1A, Zb2n, Zb2n + 128, NN << 3, 384};
        P.s[1] = RSeg{cntL, rb1L, Zb2e, Zb2e + 128, NE << 3, 640};
        P.s[2] = RSeg{cntU, rb1U, Zb2e, Zb2e + 384, NE << 3, 640};
        int n = (NN << 3) + 2 * (NE << 3);
        spmm16_kernel<<<dim3((n + 255) / 256), dim3(256), 0, stream>>>(P);
    }

    // ---- D5: layer-2 GEMM + head with fused hop-2 (M=32 tiles, striped, 8 waves) ----
    {
        G2Args G2{Zb2n, Zb2e, nW1T, eW2T, fnWT, feWT,
                  nb1s, eb1, fnb, feb,
                  cntA, cntL, cntU, rb1A, rb1L, rb1U,
                  (float*)d_out, (float*)d_out + 262144};
        gemm2_head<<<dim3(384), dim3(512), 0, stream>>>(G2);
    }
}

// Round 11
// 157.450 us; speedup vs baseline: 1.0431x; 1.0431x over previous
//
#include <hip/hip_runtime.h>

#define NN 4096
#define NE 8192
#define NLG 32768
#define CAP 32

typedef unsigned int u32;
typedef unsigned short u16;
typedef __attribute__((ext_vector_type(4))) float f32x4;
typedef __attribute__((ext_vector_type(8))) short bf16x8;
typedef __attribute__((ext_vector_type(8))) unsigned short u16x8;
typedef __attribute__((ext_vector_type(4))) unsigned short u16x4;

__device__ __forceinline__ float bf2f(u16 u) { return __uint_as_float(((u32)u) << 16); }
__device__ __forceinline__ u16 f2bf(float f) {
    u32 x = __float_as_uint(f);
    return (u16)((x + 0x7fffu + ((x >> 16) & 1u)) >> 16);  // RNE
}

// ================= K1: prep (converts/transposes/bias) + bucket append, fused =================
struct PAArgs {
    const float *x, *ex;
    const float *nW0, *nW1, *eWl0, *eWu0, *eWl1, *eWu1, *fnW, *feW, *nb0, *nb1;
    const int *nei, *eil, *eiu;
    u32 *cntA, *cntL, *cntU;            // raw counters (zeroed by memset)
    u32 *colA, *colL, *colU, *eidL, *eidU;
    u16 *Zb1n, *Zb1e, *nW0T, *nW1T, *eW1T, *eW2T, *fnWT, *feWT;
    float *nb0s, *nb1s;
};

// 4-wide transpose: thread reads 16B coalesced (4 consecutive nn of src row kk),
// writes 4 elems down dst's contiguous-fast kk dim (L2-absorbed scatter).
__device__ __forceinline__ void wtrK4(const float* src, u16* dst, u32 i, int Kp, int Nw, int ld, int kofs) {
    int n4 = i / Kp, kk = i - n4 * Kp, nn = n4 * 4;
    f32x4 v = *(const f32x4*)(src + (size_t)kk * Nw + nn);
#pragma unroll
    for (int e = 0; e < 4; ++e) dst[(size_t)(nn + e) * ld + kofs + kk] = f2bf(v[e]);
}
__device__ __forceinline__ void wtrS4(const float* sa, const float* sb, u16* dst, u32 i, int Kp, int Nw, int ld) {
    int n4 = i / Kp, kk = i - n4 * Kp, nn = n4 * 4;
    f32x4 va = *(const f32x4*)(sa + (size_t)kk * Nw + nn);
    f32x4 vb = *(const f32x4*)(sb + (size_t)kk * Nw + nn);
#pragma unroll
    for (int e = 0; e < 4; ++e) dst[(size_t)(nn + e) * ld + kk] = f2bf(va[e] + vb[e]);
}

__global__ __launch_bounds__(256) void prep_append(PAArgs A) {
    const u32 gid = blockIdx.x * blockDim.x + threadIdx.x;
    const u32 gsz = gridDim.x * blockDim.x;
    const u32 C0 = 32768;                 // x conv (8-col items)
    const u32 C1 = C0 + 32768;            // ex conv (8-col items)
    const u32 C2 = C1 + 6144;             // nW0T (Kp=192, /4)
    const u32 C3 = C2 + 12288;            // nW1T (Kp=384, /4)
    const u32 C4 = C3 + 1024;             // eW1T sum block (Kp=32, /4)
    const u32 C5 = C4 + 1024;             // eWl0 k=1
    const u32 C6 = C5 + 1024;             // eWl0 k=2
    const u32 C7 = C6 + 1024;             // eWu0 k=1
    const u32 C8 = C7 + 1024;             // eWu0 k=2
    const u32 C9 = C8 + 4096;             // eW2T sum block (Kp=128, /4)
    const u32 C10 = C9 + 4096;            // eWl1 k=1
    const u32 C11 = C10 + 4096;           // eWl1 k=2
    const u32 C12 = C11 + 4096;           // eWu1 k=1
    const u32 C13 = C12 + 4096;           // eWu1 k=2
    const u32 C14 = C13 + 2048;           // fnWT
    const u32 C15 = C14 + 2048;           // feWT
    const u32 C16 = C15 + 256;            // bias sums
    const u32 C17 = C16 + (NE + 2 * NLG); // append
    for (u32 i = gid; i < C17; i += gsz) {
        if (i < C0) {
            u32 t = i; int r = t >> 3, c8 = t & 7;
            f32x4 v0 = *(const f32x4*)(A.x + (size_t)t * 8);
            f32x4 v1 = *(const f32x4*)(A.x + (size_t)t * 8 + 4);
            u16x8 o;
#pragma unroll
            for (int e = 0; e < 4; ++e) { o[e] = f2bf(v0[e]); o[4 + e] = f2bf(v1[e]); }
            *(u16x8*)(A.Zb1n + (size_t)r * 192 + c8 * 8) = o;
        } else if (i < C1) {
            u32 t = i - C0; int r = t >> 2, c8 = t & 3;
            f32x4 v0 = *(const f32x4*)(A.ex + (size_t)t * 8);
            f32x4 v1 = *(const f32x4*)(A.ex + (size_t)t * 8 + 4);
            u16x8 o;
#pragma unroll
            for (int e = 0; e < 4; ++e) { o[e] = f2bf(v0[e]); o[4 + e] = f2bf(v1[e]); }
            *(u16x8*)(A.Zb1e + (size_t)r * 160 + c8 * 8) = o;
        }
        else if (i < C2)  wtrK4(A.nW0, A.nW0T, i - C1, 192, 128, 192, 0);
        else if (i < C3)  wtrK4(A.nW1, A.nW1T, i - C2, 384, 128, 384, 0);
        else if (i < C4)  wtrS4(A.eWl0, A.eWu0, A.eW1T, i - C3, 32, 128, 160);
        else if (i < C5)  wtrK4(A.eWl0 + 32 * 128,     A.eW1T, i - C4, 32, 128, 160, 32);
        else if (i < C6)  wtrK4(A.eWl0 + 2 * 32 * 128, A.eW1T, i - C5, 32, 128, 160, 64);
        else if (i < C7)  wtrK4(A.eWu0 + 32 * 128,     A.eW1T, i - C6, 32, 128, 160, 96);
        else if (i < C8)  wtrK4(A.eWu0 + 2 * 32 * 128, A.eW1T, i - C7, 32, 128, 160, 128);
        else if (i < C9)  wtrS4(A.eWl1, A.eWu1, A.eW2T, i - C8, 128, 128, 640);
        else if (i < C10) wtrK4(A.eWl1 + 128 * 128,     A.eW2T, i - C9, 128, 128, 640, 128);
        else if (i < C11) wtrK4(A.eWl1 + 2 * 128 * 128, A.eW2T, i - C10, 128, 128, 640, 256);
        else if (i < C12) wtrK4(A.eWu1 + 128 * 128,     A.eW2T, i - C11, 128, 128, 640, 384);
        else if (i < C13) wtrK4(A.eWu1 + 2 * 128 * 128, A.eW2T, i - C12, 128, 128, 640, 512);
        else if (i < C14) wtrK4(A.fnW, A.fnWT, i - C13, 128, 64, 128, 0);
        else if (i < C15) wtrK4(A.feW, A.feWT, i - C14, 128, 64, 128, 0);
        else if (i < C16) {
            u32 t = i - C15;
            if (t < 128) { float s = 0.f; for (int k = 0; k < 3; ++k) s += A.nb0[k * 128 + t]; A.nb0s[t] = s; }
            else { t -= 128; float s = 0.f; for (int k = 0; k < 3; ++k) s += A.nb1[k * 128 + t]; A.nb1s[t] = s; }
        } else {
            u32 t = i - C16;
            if (t < NE) {
                int r = A.nei[t];
                u32 p = atomicAdd(&A.cntA[r], 1u);
                if (p < CAP) A.colA[r * CAP + p] = (u32)A.nei[NE + t];
            } else if (t < NE + NLG) {
                u32 e = t - NE;
                int r = A.eil[e];
                u32 p = atomicAdd(&A.cntL[r], 1u);
                if (p < CAP) { A.colL[r * CAP + p] = (u32)A.eil[NLG + e]; A.eidL[r * CAP + p] = e; }
            } else {
                u32 e = t - NE - NLG;
                int r = A.eiu[e];
                u32 p = atomicAdd(&A.cntU[r], 1u);
                if (p < CAP) { A.colU[r * CAP + p] = (u32)A.eiu[NLG + e]; A.eidU[r * CAP + p] = e; }
            }
        }
    }
}

// ================= K2: fused resolve + layer-1 hop-1 spmm =================
// Uniform 32-row blocks: A 128 + L 256 + U 256 = 640 blocks, 8 slot-threads/row.
// In-place semantics: loser/dup slots get w=0. A: first-slot-wins. L/U: max-eid-wins.
struct RHArgs {
    const u32 *cntA, *cntL, *cntU;
    const u32 *colA, *colL, *colU, *eidL, *eidU;
    const float *eal, *eau;
    uint2 *rb1A, *rb1L, *rb1U;
    u16 *Zb1n, *Zb1e;
};

__global__ __launch_bounds__(256) void resolve_hop1(RHArgs A) {
    __shared__ uint2 bkt[32][33];   // +1 pad: breaks 256B-stride bank aliasing
    __shared__ u32 jns[32];
    const int b = blockIdx.x, tid = threadIdx.x;
    const int seg = (b < 128) ? 0 : (b < 384 ? 1 : 2);   // A / L / U
    const int rowbase = (seg == 0 ? b : (seg == 1 ? b - 128 : b - 384)) * 32;
    const u32* cnt = seg == 0 ? A.cntA : (seg == 1 ? A.cntL : A.cntU);
    const u32* col = seg == 0 ? A.colA : (seg == 1 ? A.colL : A.colU);
    uint2* rb = seg == 0 ? A.rb1A : (seg == 1 ? A.rb1L : A.rb1U);

    // ---- phase A: resolve into LDS + global rb1 (8 slot-threads/row) ----
    {
        const int lr = tid >> 3, s = tid & 7;
        const int row = rowbase + lr;
        u32 jn = cnt[row]; if (jn > CAP) jn = CAP;
        if (s == 0) jns[lr] = jn;
        const u32* cp = col + row * CAP;
        if (seg == 0) {
            for (u32 j = s; j < jn; j += 8) {
                u32 cj = cp[j];
                float w = 1.0f;
                for (u32 j2 = 0; j2 < j; ++j2) if (cp[j2] == cj) { w = 0.0f; break; }
                uint2 v = make_uint2(cj, __float_as_uint(w));
                bkt[lr][j] = v; rb[row * CAP + j] = v;
            }
        } else {
            const u32* ep = (seg == 1 ? A.eidL : A.eidU) + row * CAP;
            const float* wsr = seg == 1 ? A.eal : A.eau;
            for (u32 j = s; j < jn; j += 8) {
                u32 cj = cp[j], ej = ep[j];
                float w = wsr[ej];
                for (u32 j2 = 0; j2 < jn; ++j2)
                    if (j2 != j && cp[j2] == cj && ep[j2] > ej) { w = 0.0f; break; }
                uint2 v = make_uint2(cj, __float_as_uint(w));
                bkt[lr][j] = v; rb[row * CAP + j] = v;
            }
        }
    }
    __syncthreads();

    // ---- phase B: hop-1 gather using LDS buckets (8 col-groups/row) ----
    const int lr2 = tid >> 3, g = tid & 7;
    const int row2 = rowbase + lr2;
    const u32 jn2 = jns[lr2];
    if (seg == 0) {
        // node: 64 cols = 8 groups x 8
        const u16* srcg = A.Zb1n + g * 8;
        float acc[8] = {};
        for (u32 j = 0; j < jn2; ++j) {
            uint2 q = bkt[lr2][j];
            u16x8 xv = *(const u16x8*)(srcg + (size_t)q.x * 192);
            float w = __uint_as_float(q.y);
#pragma unroll
            for (int e = 0; e < 8; ++e) acc[e] = fmaf(w, bf2f(xv[e]), acc[e]);
        }
        u16x8 o;
#pragma unroll
        for (int e = 0; e < 8; ++e) o[e] = f2bf(acc[e]);
        *(u16x8*)(A.Zb1n + 64 + (size_t)row2 * 192 + g * 8) = o;
    } else {
        // edge: 32 cols = 8 groups x 4
        const u16* srcg = A.Zb1e + g * 4;
        u16* dst = seg == 1 ? A.Zb1e + 32 : A.Zb1e + 96;
        float acc[4] = {};
        for (u32 j = 0; j < jn2; ++j) {
            uint2 q = bkt[lr2][j];
            u16x4 xv = *(const u16x4*)(srcg + (size_t)q.x * 160);
            float w = __uint_as_float(q.y);
#pragma unroll
            for (int e = 0; e < 4; ++e) acc[e] = fmaf(w, bf2f(xv[e]), acc[e]);
        }
        u16x4 o;
#pragma unroll
        for (int e = 0; e < 4; ++e) o[e] = f2bf(acc[e]);
        *(u16x4*)(dst + (size_t)row2 * 160 + g * 4) = o;
    }
}

// ================= layer-2 hop-1 spmm: 8 threads/row, dual 8-col slices =================
struct RSeg { const u32* cnt; const uint2* rb; const u16* src; u16* dst; int n; int ld; };
struct Seg3 { RSeg s[3]; };

__device__ __forceinline__ void spmm_row16(const RSeg& s, int t) {
    int row = t >> 3, g = t & 7;
    u32 jn = s.cnt[row]; if (jn > CAP) jn = CAP;
    const uint2* bp = s.rb + (size_t)row * CAP;
    const u16* s0 = s.src + g * 8;
    const u16* s1 = s.src + g * 8 + 64;
    float acc[16] = {};
    u32 j = 0;
    for (; j + 2 <= jn; j += 2) {
        uint2 q0 = bp[j], q1 = bp[j + 1];
        u16x8 a0 = *(const u16x8*)(s0 + (size_t)q0.x * s.ld);
        u16x8 b0 = *(const u16x8*)(s1 + (size_t)q0.x * s.ld);
        u16x8 a1 = *(const u16x8*)(s0 + (size_t)q1.x * s.ld);
        u16x8 b1 = *(const u16x8*)(s1 + (size_t)q1.x * s.ld);
        float w0 = __uint_as_float(q0.y), w1 = __uint_as_float(q1.y);
#pragma unroll
        for (int e = 0; e < 8; ++e) {
            acc[e]     = fmaf(w0, bf2f(a0[e]), acc[e]);
            acc[8 + e] = fmaf(w0, bf2f(b0[e]), acc[8 + e]);
            acc[e]     = fmaf(w1, bf2f(a1[e]), acc[e]);
            acc[8 + e] = fmaf(w1, bf2f(b1[e]), acc[8 + e]);
        }
    }
    for (; j < jn; ++j) {
        uint2 q = bp[j];
        u16x8 a0 = *(const u16x8*)(s0 + (size_t)q.x * s.ld);
        u16x8 b0 = *(const u16x8*)(s1 + (size_t)q.x * s.ld);
        float w = __uint_as_float(q.y);
#pragma unroll
        for (int e = 0; e < 8; ++e) {
            acc[e]     = fmaf(w, bf2f(a0[e]), acc[e]);
            acc[8 + e] = fmaf(w, bf2f(b0[e]), acc[8 + e]);
        }
    }
    u16x8 o0, o1;
#pragma unroll
    for (int e = 0; e < 8; ++e) { o0[e] = f2bf(acc[e]); o1[e] = f2bf(acc[8 + e]); }
    *(u16x8*)(s.dst + (size_t)row * s.ld + g * 8) = o0;
    *(u16x8*)(s.dst + (size_t)row * s.ld + g * 8 + 64) = o1;
}

__global__ __launch_bounds__(256) void spmm16_kernel(Seg3 P) {
    int id = blockIdx.x * blockDim.x + threadIdx.x;
    int base = 0;
#pragma unroll
    for (int i = 0; i < 3; ++i) {
        int n = P.s[i].n;
        if (id < base + n) { spmm_row16(P.s[i], id - base); return; }
        base += n;
    }
}

// ================= K4: layer-1 GEMM with fused hop-2 =================
// 1 tile/block (grid 768, striped node/edge), 4 waves x 32 N-cols.
// 256 threads stage hop-2 (16 thr/row, u16x4 slices); barrier AFTER global-K MFMA.
// node A-tile: k[0,128) global (x|hop1), k[128,192) LDS (hop2)
// edge A-tile: k[0,64) g, k[64,96) LDS(L2), k[96,128) g, k[128,160) LDS(U2)
struct G1Args {
    const u16 *Zb1n, *Zb1e, *nW0T, *eW1T;
    const float *nb0s, *eb0;
    const u32 *cntA, *cntL, *cntU;
    const uint2 *rb1A, *rb1L, *rb1U;
    u16 *Zb2n, *Zb2e;
};

__global__ __launch_bounds__(256) void gemm1_kernel(G1Args A) {
    __shared__ u16 h2[16][72];   // stride 72: fragment reads land 2-way (free)
    const int tid = threadIdx.x;
    const int wv = tid >> 6, lane = tid & 63;
    const int bid = blockIdx.x;
    const int s = (bid % 3) * 256 + bid / 3;   // stripe: mix node/edge through launch order
    const bool node = s < 256;
    const int m0 = (node ? s : s - 256) * 16;

    // ---- stage hop2 (256 threads, 16 thr/row, 4-col slices) ----
    // node: 64 cols (16 x 4). edge: L2 32 cols (g 0..7), U2 32 cols (g 8..15).
    {
        const int lr = tid >> 4, g = tid & 15;
        const u32* cnt; const uint2* rb; const u16* src; int ld, dc;
        if (node) { cnt = A.cntA; rb = A.rb1A; src = A.Zb1n + 64 + g * 4; ld = 192; dc = g * 4; }
        else {
            const bool isL = g < 8; const int gg = isL ? g : g - 8;
            cnt = isL ? A.cntL : A.cntU; rb = isL ? A.rb1L : A.rb1U;
            src = (isL ? A.Zb1e + 32 : A.Zb1e + 96) + gg * 4; ld = 160;
            dc = (isL ? 0 : 32) + gg * 4;
        }
        const int row = m0 + lr;
        u32 jn = cnt[row]; if (jn > CAP) jn = CAP;
        const uint2* bp = rb + (size_t)row * CAP;
        float acc[4] = {};
        for (u32 j = 0; j < jn; ++j) {
            uint2 qe = bp[j];
            float w = __uint_as_float(qe.y);
            u16x4 a0 = *(const u16x4*)(src + (size_t)qe.x * ld);
#pragma unroll
            for (int e = 0; e < 4; ++e) acc[e] = fmaf(w, bf2f(a0[e]), acc[e]);
        }
        u16x4 o0;
#pragma unroll
        for (int e = 0; e < 4; ++e) o0[e] = f2bf(acc[e]);
        *(u16x4*)&h2[lr][dc] = o0;
    }

    // ---- MFMA GEMM, split-K; wave = 32 N-cols; barrier after global-K ----
    const int c = lane & 15, koff = (lane >> 4) * 8;
    const int n0 = wv * 32;
    f32x4 acc[2] = {};
    const u16* Lr = &h2[c][koff];
    if (node) {
        const u16* Ap = A.Zb1n + (size_t)(m0 + c) * 192 + koff;
        const u16* Wp = A.nW0T + (size_t)(n0 + c) * 192 + koff;
        const size_t ws = (size_t)16 * 192;
#pragma unroll
        for (int k0 = 0; k0 < 128; k0 += 32) {
            bf16x8 af = *(const bf16x8*)(Ap + k0);
#pragma unroll
            for (int nt = 0; nt < 2; ++nt)
                acc[nt] = __builtin_amdgcn_mfma_f32_16x16x32_bf16(af, *(const bf16x8*)(Wp + nt * ws + k0), acc[nt], 0, 0, 0);
        }
        __syncthreads();
#pragma unroll
        for (int k0 = 128; k0 < 192; k0 += 32) {
            bf16x8 af = *(const bf16x8*)(Lr + (k0 - 128));
#pragma unroll
            for (int nt = 0; nt < 2; ++nt)
                acc[nt] = __builtin_amdgcn_mfma_f32_16x16x32_bf16(af, *(const bf16x8*)(Wp + nt * ws + k0), acc[nt], 0, 0, 0);
        }
        const int orow = m0 + (lane >> 4) * 4;
#pragma unroll
        for (int nt = 0; nt < 2; ++nt) {
            int col = n0 + nt * 16 + c;
            float bv = A.nb0s[col];
#pragma unroll
            for (int r = 0; r < 4; ++r)
                A.Zb2n[(size_t)(orow + r) * 384 + col] = f2bf(fmaxf(acc[nt][r] + bv, 0.f));
        }
    } else {
        const u16* Ap = A.Zb1e + (size_t)(m0 + c) * 160 + koff;
        const u16* Wp = A.eW1T + (size_t)(n0 + c) * 160 + koff;
        const size_t ws = (size_t)16 * 160;
        bf16x8 af;
        af = *(const bf16x8*)(Ap + 0);
#pragma unroll
        for (int nt = 0; nt < 2; ++nt)
            acc[nt] = __builtin_amdgcn_mfma_f32_16x16x32_bf16(af, *(const bf16x8*)(Wp + nt * ws + 0), acc[nt], 0, 0, 0);
        af = *(const bf16x8*)(Ap + 32);
#pragma unroll
        for (int nt = 0; nt < 2; ++nt)
            acc[nt] = __builtin_amdgcn_mfma_f32_16x16x32_bf16(af, *(const bf16x8*)(Wp + nt * ws + 32), acc[nt], 0, 0, 0);
        af = *(const bf16x8*)(Ap + 96);
#pragma unroll
        for (int nt = 0; nt < 2; ++nt)
            acc[nt] = __builtin_amdgcn_mfma_f32_16x16x32_bf16(af, *(const bf16x8*)(Wp + nt * ws + 96), acc[nt], 0, 0, 0);
        __syncthreads();
        af = *(const bf16x8*)(Lr + 0);      // L2 hop2, kabs 64
#pragma unroll
        for (int nt = 0; nt < 2; ++nt)
            acc[nt] = __builtin_amdgcn_mfma_f32_16x16x32_bf16(af, *(const bf16x8*)(Wp + nt * ws + 64), acc[nt], 0, 0, 0);
        af = *(const bf16x8*)(Lr + 32);     // U2 hop2, kabs 128
#pragma unroll
        for (int nt = 0; nt < 2; ++nt)
            acc[nt] = __builtin_amdgcn_mfma_f32_16x16x32_bf16(af, *(const bf16x8*)(Wp + nt * ws + 128), acc[nt], 0, 0, 0);
        const int orow = m0 + (lane >> 4) * 4;
#pragma unroll
        for (int nt = 0; nt < 2; ++nt) {
            int col = n0 + nt * 16 + c;
            float bv = A.eb0[col];
#pragma unroll
            for (int r = 0; r < 4; ++r)
                A.Zb2e[(size_t)(orow + r) * 640 + col] = f2bf(fmaxf(acc[nt][r] + bv, 0.f));
        }
    }
}

// ================= K6: layer-2 GEMM + head with fused hop-2 (R9 structure) =================
// 1 tile/block (grid 768, striped), 8 waves x 16 N-cols (512 thr). 512 threads stage
// hop-2 (32 thr/row). Barrier after global-K. g2 padded to 136 (head reads 2-way).
// node: k[0,256) global (h|hop1), k[256,384) LDS
// edge: k[0,256)+k[384,512) global, then LDS(L2 k[256,384)), LDS(U2 k[512,640))
struct G2Args {
    const u16 *Zb2n, *Zb2e, *nW1T, *eW2T, *fnWT, *feWT;
    const float *nb1s, *eb1, *fnb, *feb;
    const u32 *cntA, *cntL, *cntU;
    const uint2 *rb1A, *rb1L, *rb1U;
    float *outn, *oute;
};

__global__ __launch_bounds__(512) void gemm2_head(G2Args A) {
    __shared__ u16 h2[16][264];   // stride 264: fragment reads land 2-way
    __shared__ u16 g2[16][136];   // +8 pad: head reads 2-way instead of 16-way
    const int tid = threadIdx.x;
    const int wv = tid >> 6, lane = tid & 63;
    const int bid = blockIdx.x;
    const int s = (bid % 3) * 256 + bid / 3;   // stripe: mix node/edge through launch order
    const bool node = s < 256;
    const int m0 = (node ? s : s - 256) * 16;

    // ---- stage hop2 (512 threads, 32 thr/row) ----
    {
        const int lr = tid >> 5, g = tid & 31;
        const int row = m0 + lr;
        if (node) {
            // 128 cols: 32 x 4-col slices
            u32 jn = A.cntA[row]; if (jn > CAP) jn = CAP;
            const uint2* bp = A.rb1A + (size_t)row * CAP;
            const u16* src = A.Zb2n + 128 + g * 4;
            float acc[4] = {};
            for (u32 j = 0; j < jn; ++j) {
                uint2 qe = bp[j];
                float w = __uint_as_float(qe.y);
                u16x4 a0 = *(const u16x4*)(src + (size_t)qe.x * 384);
#pragma unroll
                for (int e = 0; e < 4; ++e) acc[e] = fmaf(w, bf2f(a0[e]), acc[e]);
            }
            u16x4 o0;
#pragma unroll
            for (int e = 0; e < 4; ++e) o0[e] = f2bf(acc[e]);
            *(u16x4*)&h2[lr][g * 4] = o0;
        } else {
            // 256 cols: g<16 -> L2 slice g (8 cols, dc g*8); g>=16 -> U2 (dc 128+(g-16)*8)
            const bool isL = g < 16; const int gg = isL ? g : g - 16;
            const u32* cnt = isL ? A.cntL : A.cntU;
            const uint2* rb = isL ? A.rb1L : A.rb1U;
            const u16* src = (isL ? A.Zb2e + 128 : A.Zb2e + 384) + gg * 8;
            const int dc = (isL ? 0 : 128) + gg * 8;
            u32 jn = cnt[row]; if (jn > CAP) jn = CAP;
            const uint2* bp = rb + (size_t)row * CAP;
            float acc[8] = {};
            for (u32 j = 0; j < jn; ++j) {
                uint2 qe = bp[j];
                float w = __uint_as_float(qe.y);
                u16x8 a0 = *(const u16x8*)(src + (size_t)qe.x * 640);
#pragma unroll
                for (int e = 0; e < 8; ++e) acc[e] = fmaf(w, bf2f(a0[e]), acc[e]);
            }
            u16x8 o0;
#pragma unroll
            for (int e = 0; e < 8; ++e) o0[e] = f2bf(acc[e]);
            *(u16x8*)&h2[lr][dc] = o0;
        }
    }

    // ---- layer-2 GEMM: wave wv computes 16 N-cols; barrier after global-K ----
    const int c = lane & 15, q = lane >> 4, koff = q * 8;
    f32x4 acc = {};
    const u16* Lr = &h2[c][koff];
    const u16* hWT; const float *hB; float* outp;
    if (node) {
        hWT = A.fnWT; hB = A.fnb; outp = A.outn;
        const u16* Ap = A.Zb2n + (size_t)(m0 + c) * 384 + koff;
        const u16* Wp = A.nW1T + (size_t)(wv * 16 + c) * 384 + koff;
#pragma unroll
        for (int k0 = 0; k0 < 256; k0 += 32) {
            bf16x8 af = *(const bf16x8*)(Ap + k0);
            acc = __builtin_amdgcn_mfma_f32_16x16x32_bf16(af, *(const bf16x8*)(Wp + k0), acc, 0, 0, 0);
        }
        __syncthreads();
#pragma unroll
        for (int k0 = 256; k0 < 384; k0 += 32) {
            bf16x8 af = *(const bf16x8*)(Lr + (k0 - 256));
            acc = __builtin_amdgcn_mfma_f32_16x16x32_bf16(af, *(const bf16x8*)(Wp + k0), acc, 0, 0, 0);
        }
        {
            int col = wv * 16 + c;
            float bv = A.nb1s[col];
#pragma unroll
            for (int r = 0; r < 4; ++r)
                g2[q * 4 + r][col] = f2bf(fmaxf(acc[r] + bv, 0.f));
        }
    } else {
        hWT = A.feWT; hB = A.feb; outp = A.oute;
        const u16* Ap = A.Zb2e + (size_t)(m0 + c) * 640 + koff;
        const u16* Wp = A.eW2T + (size_t)(wv * 16 + c) * 640 + koff;
#pragma unroll
        for (int k0 = 0; k0 < 256; k0 += 32) {
            bf16x8 af = *(const bf16x8*)(Ap + k0);
            acc = __builtin_amdgcn_mfma_f32_16x16x32_bf16(af, *(const bf16x8*)(Wp + k0), acc, 0, 0, 0);
        }
#pragma unroll
        for (int k0 = 384; k0 < 512; k0 += 32) {
            bf16x8 af = *(const bf16x8*)(Ap + k0);
            acc = __builtin_amdgcn_mfma_f32_16x16x32_bf16(af, *(const bf16x8*)(Wp + k0), acc, 0, 0, 0);
        }
        __syncthreads();
#pragma unroll
        for (int k0 = 256; k0 < 384; k0 += 32) {
            bf16x8 af = *(const bf16x8*)(Lr + (k0 - 256));
            acc = __builtin_amdgcn_mfma_f32_16x16x32_bf16(af, *(const bf16x8*)(Wp + k0), acc, 0, 0, 0);
        }
#pragma unroll
        for (int k0 = 512; k0 < 640; k0 += 32) {
            bf16x8 af = *(const bf16x8*)(Lr + (128 + k0 - 512));
            acc = __builtin_amdgcn_mfma_f32_16x16x32_bf16(af, *(const bf16x8*)(Wp + k0), acc, 0, 0, 0);
        }
        {
            int col = wv * 16 + c;
            float bv = A.eb1[col];
#pragma unroll
            for (int r = 0; r < 4; ++r)
                g2[q * 4 + r][col] = f2bf(fmaxf(acc[r] + bv, 0.f));
        }
    }
    __syncthreads();

    // ---- head: waves 0..3 produce 16 output cols each ----
    if (wv < 4) {
        f32x4 hacc = {};
        const u16* Hp = hWT + (size_t)(wv * 16 + c) * 128 + koff;
#pragma unroll
        for (int k0 = 0; k0 < 128; k0 += 32) {
            bf16x8 af = *(const bf16x8*)(&g2[c][koff + k0]);
            bf16x8 bf = *(const bf16x8*)(Hp + k0);
            hacc = __builtin_amdgcn_mfma_f32_16x16x32_bf16(af, bf, hacc, 0, 0, 0);
        }
        int col = wv * 16 + c;
        float bv = hB[col];
#pragma unroll
        for (int r = 0; r < 4; ++r)
            outp[(size_t)(m0 + q * 4 + r) * 64 + col] = hacc[r] + bv;
    }
}

// ================= launch =================
extern "C" void kernel_launch(void* const* d_in, const int* in_sizes, int n_in,
                              void* d_out, int out_size, void* d_ws, size_t ws_size,
                              hipStream_t stream)
{
    const float* x    = (const float*)d_in[0];
    const float* ex   = (const float*)d_in[1];
    const int*   nei  = (const int*)d_in[2];
    const int*   eil  = (const int*)d_in[3];
    const float* eal  = (const float*)d_in[4];
    const int*   eiu  = (const int*)d_in[5];
    const float* eau  = (const float*)d_in[6];
    const float* nW0  = (const float*)d_in[7];
    const float* nb0  = (const float*)d_in[8];
    const float* nW1  = (const float*)d_in[9];
    const float* nb1  = (const float*)d_in[10];
    const float* fnW  = (const float*)d_in[11];
    const float* fnb  = (const float*)d_in[12];
    const float* eWl0 = (const float*)d_in[13];
    const float* eWu0 = (const float*)d_in[14];
    const float* eb0  = (const float*)d_in[15];
    const float* eWl1 = (const float*)d_in[16];
    const float* eWu1 = (const float*)d_in[17];
    const float* eb1  = (const float*)d_in[18];
    const float* feW  = (const float*)d_in[19];
    const float* feb  = (const float*)d_in[20];

    char* wsb = (char*)d_ws;
    size_t off = 0;
    auto alloc = [&](size_t bytes) { void* p = wsb + off; off += (bytes + 255) & ~(size_t)255; return p; };

    // ---- zeroed region (single small memset): raw append counters only ----
    u32* cntA = (u32*)alloc(NN * 4);
    u32* cntL = (u32*)alloc(NE * 4);
    u32* cntU = (u32*)alloc(NE * 4);
    size_t zbytes = off;   // ~82 KB

    uint2* rb1A = (uint2*)alloc((size_t)NN * CAP * 8);
    uint2* rb1L = (uint2*)alloc((size_t)NE * CAP * 8);
    uint2* rb1U = (uint2*)alloc((size_t)NE * CAP * 8);

    u32* colA = (u32*)alloc((size_t)NN * CAP * 4);
    u32* colL = (u32*)alloc((size_t)NE * CAP * 4);
    u32* colU = (u32*)alloc((size_t)NE * CAP * 4);
    u32* eidL = (u32*)alloc((size_t)NE * CAP * 4);
    u32* eidU = (u32*)alloc((size_t)NE * CAP * 4);

    u16* Zb1n = (u16*)alloc((size_t)4096 * 192 * 2);
    u16* Zb1e = (u16*)alloc((size_t)8192 * 160 * 2);
    u16* Zb2n = (u16*)alloc((size_t)4096 * 384 * 2);
    u16* Zb2e = (u16*)alloc((size_t)8192 * 640 * 2);

    u16* nW0T = (u16*)alloc((size_t)128 * 192 * 2);
    u16* nW1T = (u16*)alloc((size_t)128 * 384 * 2);
    u16* eW1T = (u16*)alloc((size_t)128 * 160 * 2);
    u16* eW2T = (u16*)alloc((size_t)128 * 640 * 2);
    u16* fnWT = (u16*)alloc((size_t)64 * 128 * 2);
    u16* feWT = (u16*)alloc((size_t)64 * 128 * 2);
    float* nb0s = (float*)alloc(128 * 4);
    float* nb1s = (float*)alloc(128 * 4);

    // ---- D0: zero counters (~82 KB) ----
    hipMemsetAsync(d_ws, 0, zbytes, stream);

    // ---- D1: prep + append ----
    PAArgs PA{x, ex, nW0, nW1, eWl0, eWu0, eWl1, eWu1, fnW, feW, nb0, nb1,
              nei, eil, eiu,
              cntA, cntL, cntU, colA, colL, colU, eidL, eidU,
              Zb1n, Zb1e, nW0T, nW1T, eW1T, eW2T, fnWT, feWT, nb0s, nb1s};
    prep_append<<<dim3(736), dim3(256), 0, stream>>>(PA);

    // ---- D2: fused resolve + layer-1 hop-1 (640 x 32-row blocks) ----
    RHArgs RH{cntA, cntL, cntU, colA, colL, colU, eidL, eidU, eal, eau,
              rb1A, rb1L, rb1U, Zb1n, Zb1e};
    resolve_hop1<<<dim3(640), dim3(256), 0, stream>>>(RH);

    // ---- D3: layer-1 GEMMs with fused hop-2 (striped tiles, 4 waves) ----
    {
        G1Args G1{Zb1n, Zb1e, nW0T, eW1T, nb0s, eb0,
                  cntA, cntL, cntU, rb1A, rb1L, rb1U, Zb2n, Zb2e};
        gemm1_kernel<<<dim3(768), dim3(256), 0, stream>>>(G1);
    }

    // ---- D4: layer-2 hop-1 (8 thr/row, dual slices) ----
    {
        Seg3 P;
        P.s[0] = RSeg{cntA, rb1A, Zb2n, Zb2n + 128, NN << 3, 384};
        P.s[1] = RSeg{cntL, rb1L, Zb2e, Zb2e + 128, NE << 3, 640};
        P.s[2] = RSeg{cntU, rb1U, Zb2e, Zb2e + 384, NE << 3, 640};
        int n = (NN << 3) + 2 * (NE << 3);
        spmm16_kernel<<<dim3((n + 255) / 256), dim3(256), 0, stream>>>(P);
    }

    // ---- D5: layer-2 GEMM + head with fused hop-2 (striped tiles, 8 waves) ----
    {
        G2Args G2{Zb2n, Zb2e, nW1T, eW2T, fnWT, feWT,
                  nb1s, eb1, fnb, feb,
                  cntA, cntL, cntU, rb1A, rb1L, rb1U,
                  (float*)d_out, (float*)d_out + 262144};
        gemm2_head<<<dim3(768), dim3(512), 0, stream>>>(G2);
    }
}

// Round 12
// 155.172 us; speedup vs baseline: 1.0584x; 1.0147x over previous
//
#include <hip/hip_runtime.h>

#define NN 4096
#define NE 8192
#define NLG 32768
#define CAP 32

typedef unsigned int u32;
typedef unsigned short u16;
typedef __attribute__((ext_vector_type(4))) float f32x4;
typedef __attribute__((ext_vector_type(8))) short bf16x8;
typedef __attribute__((ext_vector_type(8))) unsigned short u16x8;
typedef __attribute__((ext_vector_type(4))) unsigned short u16x4;

__device__ __forceinline__ float bf2f(u16 u) { return __uint_as_float(((u32)u) << 16); }
__device__ __forceinline__ u16 f2bf(float f) {
    u32 x = __float_as_uint(f);
    return (u16)((x + 0x7fffu + ((x >> 16) & 1u)) >> 16);  // RNE
}

// ================= K1: prep (converts/transposes/bias) + bucket append, fused =================
struct PAArgs {
    const float *x, *ex;
    const float *nW0, *nW1, *eWl0, *eWu0, *eWl1, *eWu1, *fnW, *feW, *nb0, *nb1;
    const int *nei, *eil, *eiu;
    u32 *cntA, *cntL, *cntU;            // raw counters (zeroed by memset)
    u32 *colA, *colL, *colU, *eidL, *eidU;
    u16 *Zb1n, *Zb1e, *nW0T, *nW1T, *eW1T, *eW2T, *fnWT, *feWT;
    float *nb0s, *nb1s;
};

// 4-wide transpose: thread reads 16B coalesced (4 consecutive nn of src row kk),
// writes 4 elems down dst's contiguous-fast kk dim (L2-absorbed scatter).
__device__ __forceinline__ void wtrK4(const float* src, u16* dst, u32 i, int Kp, int Nw, int ld, int kofs) {
    int n4 = i / Kp, kk = i - n4 * Kp, nn = n4 * 4;
    f32x4 v = *(const f32x4*)(src + (size_t)kk * Nw + nn);
#pragma unroll
    for (int e = 0; e < 4; ++e) dst[(size_t)(nn + e) * ld + kofs + kk] = f2bf(v[e]);
}
__device__ __forceinline__ void wtrS4(const float* sa, const float* sb, u16* dst, u32 i, int Kp, int Nw, int ld) {
    int n4 = i / Kp, kk = i - n4 * Kp, nn = n4 * 4;
    f32x4 va = *(const f32x4*)(sa + (size_t)kk * Nw + nn);
    f32x4 vb = *(const f32x4*)(sb + (size_t)kk * Nw + nn);
#pragma unroll
    for (int e = 0; e < 4; ++e) dst[(size_t)(nn + e) * ld + kk] = f2bf(va[e] + vb[e]);
}

__global__ __launch_bounds__(256) void prep_append(PAArgs A) {
    const u32 gid = blockIdx.x * blockDim.x + threadIdx.x;
    const u32 gsz = gridDim.x * blockDim.x;
    const u32 C0 = 32768;                 // x conv (8-col items)
    const u32 C1 = C0 + 32768;            // ex conv (8-col items)
    const u32 C2 = C1 + 6144;             // nW0T (Kp=192, /4)
    const u32 C3 = C2 + 12288;            // nW1T (Kp=384, /4)
    const u32 C4 = C3 + 1024;             // eW1T sum block (Kp=32, /4)
    const u32 C5 = C4 + 1024;             // eWl0 k=1
    const u32 C6 = C5 + 1024;             // eWl0 k=2
    const u32 C7 = C6 + 1024;             // eWu0 k=1
    const u32 C8 = C7 + 1024;             // eWu0 k=2
    const u32 C9 = C8 + 4096;             // eW2T sum block (Kp=128, /4)
    const u32 C10 = C9 + 4096;            // eWl1 k=1
    const u32 C11 = C10 + 4096;           // eWl1 k=2
    const u32 C12 = C11 + 4096;           // eWu1 k=1
    const u32 C13 = C12 + 4096;           // eWu1 k=2
    const u32 C14 = C13 + 2048;           // fnWT
    const u32 C15 = C14 + 2048;           // feWT
    const u32 C16 = C15 + 256;            // bias sums
    const u32 C17 = C16 + (NE + 2 * NLG); // append
    for (u32 i = gid; i < C17; i += gsz) {
        if (i < C0) {
            u32 t = i; int r = t >> 3, c8 = t & 7;
            f32x4 v0 = *(const f32x4*)(A.x + (size_t)t * 8);
            f32x4 v1 = *(const f32x4*)(A.x + (size_t)t * 8 + 4);
            u16x8 o;
#pragma unroll
            for (int e = 0; e < 4; ++e) { o[e] = f2bf(v0[e]); o[4 + e] = f2bf(v1[e]); }
            *(u16x8*)(A.Zb1n + (size_t)r * 192 + c8 * 8) = o;
        } else if (i < C1) {
            u32 t = i - C0; int r = t >> 2, c8 = t & 3;
            f32x4 v0 = *(const f32x4*)(A.ex + (size_t)t * 8);
            f32x4 v1 = *(const f32x4*)(A.ex + (size_t)t * 8 + 4);
            u16x8 o;
#pragma unroll
            for (int e = 0; e < 4; ++e) { o[e] = f2bf(v0[e]); o[4 + e] = f2bf(v1[e]); }
            *(u16x8*)(A.Zb1e + (size_t)r * 160 + c8 * 8) = o;
        }
        else if (i < C2)  wtrK4(A.nW0, A.nW0T, i - C1, 192, 128, 192, 0);
        else if (i < C3)  wtrK4(A.nW1, A.nW1T, i - C2, 384, 128, 384, 0);
        else if (i < C4)  wtrS4(A.eWl0, A.eWu0, A.eW1T, i - C3, 32, 128, 160);
        else if (i < C5)  wtrK4(A.eWl0 + 32 * 128,     A.eW1T, i - C4, 32, 128, 160, 32);
        else if (i < C6)  wtrK4(A.eWl0 + 2 * 32 * 128, A.eW1T, i - C5, 32, 128, 160, 64);
        else if (i < C7)  wtrK4(A.eWu0 + 32 * 128,     A.eW1T, i - C6, 32, 128, 160, 96);
        else if (i < C8)  wtrK4(A.eWu0 + 2 * 32 * 128, A.eW1T, i - C7, 32, 128, 160, 128);
        else if (i < C9)  wtrS4(A.eWl1, A.eWu1, A.eW2T, i - C8, 128, 128, 640);
        else if (i < C10) wtrK4(A.eWl1 + 128 * 128,     A.eW2T, i - C9, 128, 128, 640, 128);
        else if (i < C11) wtrK4(A.eWl1 + 2 * 128 * 128, A.eW2T, i - C10, 128, 128, 640, 256);
        else if (i < C12) wtrK4(A.eWu1 + 128 * 128,     A.eW2T, i - C11, 128, 128, 640, 384);
        else if (i < C13) wtrK4(A.eWu1 + 2 * 128 * 128, A.eW2T, i - C12, 128, 128, 640, 512);
        else if (i < C14) wtrK4(A.fnW, A.fnWT, i - C13, 128, 64, 128, 0);
        else if (i < C15) wtrK4(A.feW, A.feWT, i - C14, 128, 64, 128, 0);
        else if (i < C16) {
            u32 t = i - C15;
            if (t < 128) { float s = 0.f; for (int k = 0; k < 3; ++k) s += A.nb0[k * 128 + t]; A.nb0s[t] = s; }
            else { t -= 128; float s = 0.f; for (int k = 0; k < 3; ++k) s += A.nb1[k * 128 + t]; A.nb1s[t] = s; }
        } else {
            u32 t = i - C16;
            if (t < NE) {
                int r = A.nei[t];
                u32 p = atomicAdd(&A.cntA[r], 1u);
                if (p < CAP) A.colA[r * CAP + p] = (u32)A.nei[NE + t];
            } else if (t < NE + NLG) {
                u32 e = t - NE;
                int r = A.eil[e];
                u32 p = atomicAdd(&A.cntL[r], 1u);
                if (p < CAP) { A.colL[r * CAP + p] = (u32)A.eil[NLG + e]; A.eidL[r * CAP + p] = e; }
            } else {
                u32 e = t - NE - NLG;
                int r = A.eiu[e];
                u32 p = atomicAdd(&A.cntU[r], 1u);
                if (p < CAP) { A.colU[r * CAP + p] = (u32)A.eiu[NLG + e]; A.eidU[r * CAP + p] = e; }
            }
        }
    }
}

// ================= K2: fused resolve + layer-1 hop-1 spmm =================
// Uniform 32-row blocks: A 128 + L 256 + U 256 = 640 blocks, 8 slot-threads/row.
// In-place semantics: loser/dup slots get w=0. A: first-slot-wins. L/U: max-eid-wins.
struct RHArgs {
    const u32 *cntA, *cntL, *cntU;
    const u32 *colA, *colL, *colU, *eidL, *eidU;
    const float *eal, *eau;
    uint2 *rb1A, *rb1L, *rb1U;
    u16 *Zb1n, *Zb1e;
};

__global__ __launch_bounds__(256) void resolve_hop1(RHArgs A) {
    __shared__ uint2 bkt[32][33];   // +1 pad: breaks 256B-stride bank aliasing
    __shared__ u32 jns[32];
    const int b = blockIdx.x, tid = threadIdx.x;
    const int seg = (b < 128) ? 0 : (b < 384 ? 1 : 2);   // A / L / U
    const int rowbase = (seg == 0 ? b : (seg == 1 ? b - 128 : b - 384)) * 32;
    const u32* cnt = seg == 0 ? A.cntA : (seg == 1 ? A.cntL : A.cntU);
    const u32* col = seg == 0 ? A.colA : (seg == 1 ? A.colL : A.colU);
    uint2* rb = seg == 0 ? A.rb1A : (seg == 1 ? A.rb1L : A.rb1U);

    // ---- phase A: resolve into LDS + global rb1 (8 slot-threads/row) ----
    {
        const int lr = tid >> 3, s = tid & 7;
        const int row = rowbase + lr;
        u32 jn = cnt[row]; if (jn > CAP) jn = CAP;
        if (s == 0) jns[lr] = jn;
        const u32* cp = col + row * CAP;
        if (seg == 0) {
            for (u32 j = s; j < jn; j += 8) {
                u32 cj = cp[j];
                float w = 1.0f;
                for (u32 j2 = 0; j2 < j; ++j2) if (cp[j2] == cj) { w = 0.0f; break; }
                uint2 v = make_uint2(cj, __float_as_uint(w));
                bkt[lr][j] = v; rb[row * CAP + j] = v;
            }
        } else {
            const u32* ep = (seg == 1 ? A.eidL : A.eidU) + row * CAP;
            const float* wsr = seg == 1 ? A.eal : A.eau;
            for (u32 j = s; j < jn; j += 8) {
                u32 cj = cp[j], ej = ep[j];
                float w = wsr[ej];
                for (u32 j2 = 0; j2 < jn; ++j2)
                    if (j2 != j && cp[j2] == cj && ep[j2] > ej) { w = 0.0f; break; }
                uint2 v = make_uint2(cj, __float_as_uint(w));
                bkt[lr][j] = v; rb[row * CAP + j] = v;
            }
        }
    }
    __syncthreads();

    // ---- phase B: hop-1 gather using LDS buckets (8 col-groups/row) ----
    const int lr2 = tid >> 3, g = tid & 7;
    const int row2 = rowbase + lr2;
    const u32 jn2 = jns[lr2];
    if (seg == 0) {
        // node: 64 cols = 8 groups x 8
        const u16* srcg = A.Zb1n + g * 8;
        float acc[8] = {};
        for (u32 j = 0; j < jn2; ++j) {
            uint2 q = bkt[lr2][j];
            u16x8 xv = *(const u16x8*)(srcg + (size_t)q.x * 192);
            float w = __uint_as_float(q.y);
#pragma unroll
            for (int e = 0; e < 8; ++e) acc[e] = fmaf(w, bf2f(xv[e]), acc[e]);
        }
        u16x8 o;
#pragma unroll
        for (int e = 0; e < 8; ++e) o[e] = f2bf(acc[e]);
        *(u16x8*)(A.Zb1n + 64 + (size_t)row2 * 192 + g * 8) = o;
    } else {
        // edge: 32 cols = 8 groups x 4
        const u16* srcg = A.Zb1e + g * 4;
        u16* dst = seg == 1 ? A.Zb1e + 32 : A.Zb1e + 96;
        float acc[4] = {};
        for (u32 j = 0; j < jn2; ++j) {
            uint2 q = bkt[lr2][j];
            u16x4 xv = *(const u16x4*)(srcg + (size_t)q.x * 160);
            float w = __uint_as_float(q.y);
#pragma unroll
            for (int e = 0; e < 4; ++e) acc[e] = fmaf(w, bf2f(xv[e]), acc[e]);
        }
        u16x4 o;
#pragma unroll
        for (int e = 0; e < 4; ++e) o[e] = f2bf(acc[e]);
        *(u16x4*)(dst + (size_t)row2 * 160 + g * 4) = o;
    }
}

// ================= layer-2 hop-1 spmm: 32-row blocks, LDS-staged buckets =================
// Bucket loaded from global ONCE per row (cooperative, 8 thr/row), then 8 thr/row
// dual-slice gather reads it from LDS. j-order per thread unchanged -> bit-identical.
struct SPArgs {
    const u32 *cntA, *cntL, *cntU;
    const uint2 *rb1A, *rb1L, *rb1U;
    const u16 *Zb2n, *Zb2e;
    u16 *dn, *dl, *du;                    // dst base ptrs (Zb2n+128, Zb2e+128, Zb2e+384)
};

__global__ __launch_bounds__(256) void spmm16_kernel(SPArgs A) {
    __shared__ uint2 bkt[32][33];
    __shared__ u32 jns[32];
    const int b = blockIdx.x, tid = threadIdx.x;
    const int seg = (b < 128) ? 0 : (b < 384 ? 1 : 2);   // node / L / U
    const int rowbase = (seg == 0 ? b : (seg == 1 ? b - 128 : b - 384)) * 32;
    const u32* cnt = seg == 0 ? A.cntA : (seg == 1 ? A.cntL : A.cntU);
    const uint2* rb = seg == 0 ? A.rb1A : (seg == 1 ? A.rb1L : A.rb1U);
    const u16* src = seg == 0 ? A.Zb2n : A.Zb2e;
    u16* dst = seg == 0 ? A.dn : (seg == 1 ? A.dl : A.du);
    const int ld = seg == 0 ? 384 : 640;

    const int lr = tid >> 3, s = tid & 7;
    const int row = rowbase + lr;
    u32 jn = cnt[row]; if (jn > CAP) jn = CAP;
    if (s == 0) jns[lr] = jn;
    {   // cooperative bucket load
        const uint2* bp = rb + (size_t)row * CAP;
        for (u32 j = s; j < jn; j += 8) bkt[lr][j] = bp[j];
    }
    __syncthreads();

    const u32 jn2 = jns[lr];
    const u16* s0 = src + s * 8;
    const u16* s1 = src + s * 8 + 64;
    float acc[16] = {};
    for (u32 j = 0; j < jn2; ++j) {
        uint2 q = bkt[lr][j];
        u16x8 a0 = *(const u16x8*)(s0 + (size_t)q.x * ld);
        u16x8 b0 = *(const u16x8*)(s1 + (size_t)q.x * ld);
        float w = __uint_as_float(q.y);
#pragma unroll
        for (int e = 0; e < 8; ++e) {
            acc[e]     = fmaf(w, bf2f(a0[e]), acc[e]);
            acc[8 + e] = fmaf(w, bf2f(b0[e]), acc[8 + e]);
        }
    }
    u16x8 o0, o1;
#pragma unroll
    for (int e = 0; e < 8; ++e) { o0[e] = f2bf(acc[e]); o1[e] = f2bf(acc[8 + e]); }
    *(u16x8*)(dst + (size_t)row * ld + s * 8) = o0;
    *(u16x8*)(dst + (size_t)row * ld + s * 8 + 64) = o1;
}

// ================= K4: layer-1 GEMM with fused hop-2 =================
// 1 tile/block (grid 768, striped node/edge), 4 waves x 32 N-cols.
// Buckets cooperatively loaded to LDS once; 256 threads stage hop-2 (16 thr/row,
// u16x4 slices) from LDS buckets; barrier AFTER global-K MFMA.
// node A-tile: k[0,128) global (x|hop1), k[128,192) LDS (hop2)
// edge A-tile: k[0,64) g, k[64,96) LDS(L2), k[96,128) g, k[128,160) LDS(U2)
struct G1Args {
    const u16 *Zb1n, *Zb1e, *nW0T, *eW1T;
    const float *nb0s, *eb0;
    const u32 *cntA, *cntL, *cntU;
    const uint2 *rb1A, *rb1L, *rb1U;
    u16 *Zb2n, *Zb2e;
};

__global__ __launch_bounds__(256) void gemm1_kernel(G1Args A) {
    __shared__ u16 h2[16][72];        // stride 72: fragment reads land 2-way (free)
    __shared__ uint2 bkt2[2][16][32]; // [L|A][row][slot], [U][row][slot]
    const int tid = threadIdx.x;
    const int wv = tid >> 6, lane = tid & 63;
    const int bid = blockIdx.x;
    const int s = (bid % 3) * 256 + bid / 3;   // stripe: mix node/edge through launch order
    const bool node = s < 256;
    const int m0 = (node ? s : s - 256) * 16;

    // ---- cooperative bucket load (16 thr/row) ----
    {
        const int lr = tid >> 4, g = tid & 15;
        const int row = m0 + lr;
        if (node) {
            u32 jn = A.cntA[row]; if (jn > CAP) jn = CAP;
            const uint2* bp = A.rb1A + (size_t)row * CAP;
            for (u32 j = g; j < jn; j += 16) bkt2[0][lr][j] = bp[j];
        } else {
            const int mat = g >> 3, gg = g & 7;     // 8 thr for L, 8 for U
            const u32* cnt = mat == 0 ? A.cntL : A.cntU;
            const uint2* rb = mat == 0 ? A.rb1L : A.rb1U;
            u32 jn = cnt[row]; if (jn > CAP) jn = CAP;
            const uint2* bp = rb + (size_t)row * CAP;
            for (u32 j = gg; j < jn; j += 8) bkt2[mat][lr][j] = bp[j];
        }
    }
    __syncthreads();

    // ---- stage hop2 (256 threads, 16 thr/row, 4-col slices) from LDS buckets ----
    {
        const int lr = tid >> 4, g = tid & 15;
        const u32* cnt; const u16* src; int ld, dc, mat;
        if (node) { cnt = A.cntA; src = A.Zb1n + 64 + g * 4; ld = 192; dc = g * 4; mat = 0; }
        else {
            const bool isL = g < 8; const int gg = isL ? g : g - 8;
            cnt = isL ? A.cntL : A.cntU; mat = isL ? 0 : 1;
            src = (isL ? A.Zb1e + 32 : A.Zb1e + 96) + gg * 4; ld = 160;
            dc = (isL ? 0 : 32) + gg * 4;
        }
        const int row = m0 + lr;
        u32 jn = cnt[row]; if (jn > CAP) jn = CAP;
        float acc[4] = {};
        for (u32 j = 0; j < jn; ++j) {
            uint2 qe = bkt2[mat][lr][j];
            float w = __uint_as_float(qe.y);
            u16x4 a0 = *(const u16x4*)(src + (size_t)qe.x * ld);
#pragma unroll
            for (int e = 0; e < 4; ++e) acc[e] = fmaf(w, bf2f(a0[e]), acc[e]);
        }
        u16x4 o0;
#pragma unroll
        for (int e = 0; e < 4; ++e) o0[e] = f2bf(acc[e]);
        *(u16x4*)&h2[lr][dc] = o0;
    }

    // ---- MFMA GEMM, split-K; wave = 32 N-cols; barrier after global-K ----
    const int c = lane & 15, koff = (lane >> 4) * 8;
    const int n0 = wv * 32;
    f32x4 acc[2] = {};
    const u16* Lr = &h2[c][koff];
    if (node) {
        const u16* Ap = A.Zb1n + (size_t)(m0 + c) * 192 + koff;
        const u16* Wp = A.nW0T + (size_t)(n0 + c) * 192 + koff;
        const size_t ws = (size_t)16 * 192;
#pragma unroll
        for (int k0 = 0; k0 < 128; k0 += 32) {
            bf16x8 af = *(const bf16x8*)(Ap + k0);
#pragma unroll
            for (int nt = 0; nt < 2; ++nt)
                acc[nt] = __builtin_amdgcn_mfma_f32_16x16x32_bf16(af, *(const bf16x8*)(Wp + nt * ws + k0), acc[nt], 0, 0, 0);
        }
        __syncthreads();
#pragma unroll
        for (int k0 = 128; k0 < 192; k0 += 32) {
            bf16x8 af = *(const bf16x8*)(Lr + (k0 - 128));
#pragma unroll
            for (int nt = 0; nt < 2; ++nt)
                acc[nt] = __builtin_amdgcn_mfma_f32_16x16x32_bf16(af, *(const bf16x8*)(Wp + nt * ws + k0), acc[nt], 0, 0, 0);
        }
        const int orow = m0 + (lane >> 4) * 4;
#pragma unroll
        for (int nt = 0; nt < 2; ++nt) {
            int col = n0 + nt * 16 + c;
            float bv = A.nb0s[col];
#pragma unroll
            for (int r = 0; r < 4; ++r)
                A.Zb2n[(size_t)(orow + r) * 384 + col] = f2bf(fmaxf(acc[nt][r] + bv, 0.f));
        }
    } else {
        const u16* Ap = A.Zb1e + (size_t)(m0 + c) * 160 + koff;
        const u16* Wp = A.eW1T + (size_t)(n0 + c) * 160 + koff;
        const size_t ws = (size_t)16 * 160;
        bf16x8 af;
        af = *(const bf16x8*)(Ap + 0);
#pragma unroll
        for (int nt = 0; nt < 2; ++nt)
            acc[nt] = __builtin_amdgcn_mfma_f32_16x16x32_bf16(af, *(const bf16x8*)(Wp + nt * ws + 0), acc[nt], 0, 0, 0);
        af = *(const bf16x8*)(Ap + 32);
#pragma unroll
        for (int nt = 0; nt < 2; ++nt)
            acc[nt] = __builtin_amdgcn_mfma_f32_16x16x32_bf16(af, *(const bf16x8*)(Wp + nt * ws + 32), acc[nt], 0, 0, 0);
        af = *(const bf16x8*)(Ap + 96);
#pragma unroll
        for (int nt = 0; nt < 2; ++nt)
            acc[nt] = __builtin_amdgcn_mfma_f32_16x16x32_bf16(af, *(const bf16x8*)(Wp + nt * ws + 96), acc[nt], 0, 0, 0);
        __syncthreads();
        af = *(const bf16x8*)(Lr + 0);      // L2 hop2, kabs 64
#pragma unroll
        for (int nt = 0; nt < 2; ++nt)
            acc[nt] = __builtin_amdgcn_mfma_f32_16x16x32_bf16(af, *(const bf16x8*)(Wp + nt * ws + 64), acc[nt], 0, 0, 0);
        af = *(const bf16x8*)(Lr + 32);     // U2 hop2, kabs 128
#pragma unroll
        for (int nt = 0; nt < 2; ++nt)
            acc[nt] = __builtin_amdgcn_mfma_f32_16x16x32_bf16(af, *(const bf16x8*)(Wp + nt * ws + 128), acc[nt], 0, 0, 0);
        const int orow = m0 + (lane >> 4) * 4;
#pragma unroll
        for (int nt = 0; nt < 2; ++nt) {
            int col = n0 + nt * 16 + c;
            float bv = A.eb0[col];
#pragma unroll
            for (int r = 0; r < 4; ++r)
                A.Zb2e[(size_t)(orow + r) * 640 + col] = f2bf(fmaxf(acc[nt][r] + bv, 0.f));
        }
    }
}

// ================= K6: layer-2 GEMM + head with fused hop-2 =================
// 1 tile/block (grid 768, striped), 8 waves x 16 N-cols (512 thr). Buckets
// cooperatively loaded to LDS once; 512 threads stage hop-2 (32 thr/row) from LDS.
// Barrier after global-K. g2 padded to 136 (head reads 2-way).
// node: k[0,256) global (h|hop1), k[256,384) LDS
// edge: k[0,256)+k[384,512) global, then LDS(L2 k[256,384)), LDS(U2 k[512,640))
struct G2Args {
    const u16 *Zb2n, *Zb2e, *nW1T, *eW2T, *fnWT, *feWT;
    const float *nb1s, *eb1, *fnb, *feb;
    const u32 *cntA, *cntL, *cntU;
    const uint2 *rb1A, *rb1L, *rb1U;
    float *outn, *oute;
};

__global__ __launch_bounds__(512) void gemm2_head(G2Args A) {
    __shared__ u16 h2[16][264];       // stride 264: fragment reads land 2-way
    __shared__ u16 g2[16][136];       // +8 pad: head reads 2-way instead of 16-way
    __shared__ uint2 bkt2[2][16][32]; // [A|L][row][slot], [U][row][slot]
    const int tid = threadIdx.x;
    const int wv = tid >> 6, lane = tid & 63;
    const int bid = blockIdx.x;
    const int s = (bid % 3) * 256 + bid / 3;   // stripe: mix node/edge through launch order
    const bool node = s < 256;
    const int m0 = (node ? s : s - 256) * 16;

    // ---- cooperative bucket load (32 thr/row) ----
    {
        const int lr = tid >> 5, g = tid & 31;
        const int row = m0 + lr;
        if (node) {
            u32 jn = A.cntA[row]; if (jn > CAP) jn = CAP;
            const uint2* bp = A.rb1A + (size_t)row * CAP;
            for (u32 j = g; j < jn; j += 32) bkt2[0][lr][j] = bp[j];
        } else {
            const int mat = g >> 4, gg = g & 15;     // 16 thr for L, 16 for U
            const u32* cnt = mat == 0 ? A.cntL : A.cntU;
            const uint2* rb = mat == 0 ? A.rb1L : A.rb1U;
            u32 jn = cnt[row]; if (jn > CAP) jn = CAP;
            const uint2* bp = rb + (size_t)row * CAP;
            for (u32 j = gg; j < jn; j += 16) bkt2[mat][lr][j] = bp[j];
        }
    }
    __syncthreads();

    // ---- stage hop2 (512 threads, 32 thr/row) from LDS buckets ----
    {
        const int lr = tid >> 5, g = tid & 31;
        const int row = m0 + lr;
        if (node) {
            // 128 cols: 32 x 4-col slices
            u32 jn = A.cntA[row]; if (jn > CAP) jn = CAP;
            const u16* src = A.Zb2n + 128 + g * 4;
            float acc[4] = {};
            for (u32 j = 0; j < jn; ++j) {
                uint2 qe = bkt2[0][lr][j];
                float w = __uint_as_float(qe.y);
                u16x4 a0 = *(const u16x4*)(src + (size_t)qe.x * 384);
#pragma unroll
                for (int e = 0; e < 4; ++e) acc[e] = fmaf(w, bf2f(a0[e]), acc[e]);
            }
            u16x4 o0;
#pragma unroll
            for (int e = 0; e < 4; ++e) o0[e] = f2bf(acc[e]);
            *(u16x4*)&h2[lr][g * 4] = o0;
        } else {
            // 256 cols: g<16 -> L2 slice g (8 cols, dc g*8); g>=16 -> U2 (dc 128+(g-16)*8)
            const bool isL = g < 16; const int gg = isL ? g : g - 16;
            const u32* cnt = isL ? A.cntL : A.cntU;
            const int mat = isL ? 0 : 1;
            const u16* src = (isL ? A.Zb2e + 128 : A.Zb2e + 384) + gg * 8;
            const int dc = (isL ? 0 : 128) + gg * 8;
            u32 jn = cnt[row]; if (jn > CAP) jn = CAP;
            float acc[8] = {};
            for (u32 j = 0; j < jn; ++j) {
                uint2 qe = bkt2[mat][lr][j];
                float w = __uint_as_float(qe.y);
                u16x8 a0 = *(const u16x8*)(src + (size_t)qe.x * 640);
#pragma unroll
                for (int e = 0; e < 8; ++e) acc[e] = fmaf(w, bf2f(a0[e]), acc[e]);
            }
            u16x8 o0;
#pragma unroll
            for (int e = 0; e < 8; ++e) o0[e] = f2bf(acc[e]);
            *(u16x8*)&h2[lr][dc] = o0;
        }
    }

    // ---- layer-2 GEMM: wave wv computes 16 N-cols; barrier after global-K ----
    const int c = lane & 15, q = lane >> 4, koff = q * 8;
    f32x4 acc = {};
    const u16* Lr = &h2[c][koff];
    const u16* hWT; const float *hB; float* outp;
    if (node) {
        hWT = A.fnWT; hB = A.fnb; outp = A.outn;
        const u16* Ap = A.Zb2n + (size_t)(m0 + c) * 384 + koff;
        const u16* Wp = A.nW1T + (size_t)(wv * 16 + c) * 384 + koff;
#pragma unroll
        for (int k0 = 0; k0 < 256; k0 += 32) {
            bf16x8 af = *(const bf16x8*)(Ap + k0);
            acc = __builtin_amdgcn_mfma_f32_16x16x32_bf16(af, *(const bf16x8*)(Wp + k0), acc, 0, 0, 0);
        }
        __syncthreads();
#pragma unroll
        for (int k0 = 256; k0 < 384; k0 += 32) {
            bf16x8 af = *(const bf16x8*)(Lr + (k0 - 256));
            acc = __builtin_amdgcn_mfma_f32_16x16x32_bf16(af, *(const bf16x8*)(Wp + k0), acc, 0, 0, 0);
        }
        {
            int col = wv * 16 + c;
            float bv = A.nb1s[col];
#pragma unroll
            for (int r = 0; r < 4; ++r)
                g2[q * 4 + r][col] = f2bf(fmaxf(acc[r] + bv, 0.f));
        }
    } else {
        hWT = A.feWT; hB = A.feb; outp = A.oute;
        const u16* Ap = A.Zb2e + (size_t)(m0 + c) * 640 + koff;
        const u16* Wp = A.eW2T + (size_t)(wv * 16 + c) * 640 + koff;
#pragma unroll
        for (int k0 = 0; k0 < 256; k0 += 32) {
            bf16x8 af = *(const bf16x8*)(Ap + k0);
            acc = __builtin_amdgcn_mfma_f32_16x16x32_bf16(af, *(const bf16x8*)(Wp + k0), acc, 0, 0, 0);
        }
#pragma unroll
        for (int k0 = 384; k0 < 512; k0 += 32) {
            bf16x8 af = *(const bf16x8*)(Ap + k0);
            acc = __builtin_amdgcn_mfma_f32_16x16x32_bf16(af, *(const bf16x8*)(Wp + k0), acc, 0, 0, 0);
        }
        __syncthreads();
#pragma unroll
        for (int k0 = 256; k0 < 384; k0 += 32) {
            bf16x8 af = *(const bf16x8*)(Lr + (k0 - 256));
            acc = __builtin_amdgcn_mfma_f32_16x16x32_bf16(af, *(const bf16x8*)(Wp + k0), acc, 0, 0, 0);
        }
#pragma unroll
        for (int k0 = 512; k0 < 640; k0 += 32) {
            bf16x8 af = *(const bf16x8*)(Lr + (128 + k0 - 512));
            acc = __builtin_amdgcn_mfma_f32_16x16x32_bf16(af, *(const bf16x8*)(Wp + k0), acc, 0, 0, 0);
        }
        {
            int col = wv * 16 + c;
            float bv = A.eb1[col];
#pragma unroll
            for (int r = 0; r < 4; ++r)
                g2[q * 4 + r][col] = f2bf(fmaxf(acc[r] + bv, 0.f));
        }
    }
    __syncthreads();

    // ---- head: waves 0..3 produce 16 output cols each ----
    if (wv < 4) {
        f32x4 hacc = {};
        const u16* Hp = hWT + (size_t)(wv * 16 + c) * 128 + koff;
#pragma unroll
        for (int k0 = 0; k0 < 128; k0 += 32) {
            bf16x8 af = *(const bf16x8*)(&g2[c][koff + k0]);
            bf16x8 bf = *(const bf16x8*)(Hp + k0);
            hacc = __builtin_amdgcn_mfma_f32_16x16x32_bf16(af, bf, hacc, 0, 0, 0);
        }
        int col = wv * 16 + c;
        float bv = hB[col];
#pragma unroll
        for (int r = 0; r < 4; ++r)
            outp[(size_t)(m0 + q * 4 + r) * 64 + col] = hacc[r] + bv;
    }
}

// ================= launch =================
extern "C" void kernel_launch(void* const* d_in, const int* in_sizes, int n_in,
                              void* d_out, int out_size, void* d_ws, size_t ws_size,
                              hipStream_t stream)
{
    const float* x    = (const float*)d_in[0];
    const float* ex   = (const float*)d_in[1];
    const int*   nei  = (const int*)d_in[2];
    const int*   eil  = (const int*)d_in[3];
    const float* eal  = (const float*)d_in[4];
    const int*   eiu  = (const int*)d_in[5];
    const float* eau  = (const float*)d_in[6];
    const float* nW0  = (const float*)d_in[7];
    const float* nb0  = (const float*)d_in[8];
    const float* nW1  = (const float*)d_in[9];
    const float* nb1  = (const float*)d_in[10];
    const float* fnW  = (const float*)d_in[11];
    const float* fnb  = (const float*)d_in[12];
    const float* eWl0 = (const float*)d_in[13];
    const float* eWu0 = (const float*)d_in[14];
    const float* eb0  = (const float*)d_in[15];
    const float* eWl1 = (const float*)d_in[16];
    const float* eWu1 = (const float*)d_in[17];
    const float* eb1  = (const float*)d_in[18];
    const float* feW  = (const float*)d_in[19];
    const float* feb  = (const float*)d_in[20];

    char* wsb = (char*)d_ws;
    size_t off = 0;
    auto alloc = [&](size_t bytes) { void* p = wsb + off; off += (bytes + 255) & ~(size_t)255; return p; };

    // ---- zeroed region (single small memset): raw append counters only ----
    u32* cntA = (u32*)alloc(NN * 4);
    u32* cntL = (u32*)alloc(NE * 4);
    u32* cntU = (u32*)alloc(NE * 4);
    size_t zbytes = off;   // ~82 KB

    uint2* rb1A = (uint2*)alloc((size_t)NN * CAP * 8);
    uint2* rb1L = (uint2*)alloc((size_t)NE * CAP * 8);
    uint2* rb1U = (uint2*)alloc((size_t)NE * CAP * 8);

    u32* colA = (u32*)alloc((size_t)NN * CAP * 4);
    u32* colL = (u32*)alloc((size_t)NE * CAP * 4);
    u32* colU = (u32*)alloc((size_t)NE * CAP * 4);
    u32* eidL = (u32*)alloc((size_t)NE * CAP * 4);
    u32* eidU = (u32*)alloc((size_t)NE * CAP * 4);

    u16* Zb1n = (u16*)alloc((size_t)4096 * 192 * 2);
    u16* Zb1e = (u16*)alloc((size_t)8192 * 160 * 2);
    u16* Zb2n = (u16*)alloc((size_t)4096 * 384 * 2);
    u16* Zb2e = (u16*)alloc((size_t)8192 * 640 * 2);

    u16* nW0T = (u16*)alloc((size_t)128 * 192 * 2);
    u16* nW1T = (u16*)alloc((size_t)128 * 384 * 2);
    u16* eW1T = (u16*)alloc((size_t)128 * 160 * 2);
    u16* eW2T = (u16*)alloc((size_t)128 * 640 * 2);
    u16* fnWT = (u16*)alloc((size_t)64 * 128 * 2);
    u16* feWT = (u16*)alloc((size_t)64 * 128 * 2);
    float* nb0s = (float*)alloc(128 * 4);
    float* nb1s = (float*)alloc(128 * 4);

    // ---- D0: zero counters (~82 KB) ----
    hipMemsetAsync(d_ws, 0, zbytes, stream);

    // ---- D1: prep + append ----
    PAArgs PA{x, ex, nW0, nW1, eWl0, eWu0, eWl1, eWu1, fnW, feW, nb0, nb1,
              nei, eil, eiu,
              cntA, cntL, cntU, colA, colL, colU, eidL, eidU,
              Zb1n, Zb1e, nW0T, nW1T, eW1T, eW2T, fnWT, feWT, nb0s, nb1s};
    prep_append<<<dim3(736), dim3(256), 0, stream>>>(PA);

    // ---- D2: fused resolve + layer-1 hop-1 (640 x 32-row blocks) ----
    RHArgs RH{cntA, cntL, cntU, colA, colL, colU, eidL, eidU, eal, eau,
              rb1A, rb1L, rb1U, Zb1n, Zb1e};
    resolve_hop1<<<dim3(640), dim3(256), 0, stream>>>(RH);

    // ---- D3: layer-1 GEMMs with fused hop-2 (striped tiles, 4 waves) ----
    {
        G1Args G1{Zb1n, Zb1e, nW0T, eW1T, nb0s, eb0,
                  cntA, cntL, cntU, rb1A, rb1L, rb1U, Zb2n, Zb2e};
        gemm1_kernel<<<dim3(768), dim3(256), 0, stream>>>(G1);
    }

    // ---- D4: layer-2 hop-1 (32-row blocks, LDS buckets) ----
    {
        SPArgs SP{cntA, cntL, cntU, rb1A, rb1L, rb1U,
                  Zb2n, Zb2e, Zb2n + 128, Zb2e + 128, Zb2e + 384};
        spmm16_kernel<<<dim3(640), dim3(256), 0, stream>>>(SP);
    }

    // ---- D5: layer-2 GEMM + head with fused hop-2 (striped tiles, 8 waves) ----
    {
        G2Args G2{Zb2n, Zb2e, nW1T, eW2T, fnWT, feWT,
                  nb1s, eb1, fnb, feb,
                  cntA, cntL, cntU, rb1A, rb1L, rb1U,
                  (float*)d_out, (float*)d_out + 262144};
        gemm2_head<<<dim3(768), dim3(512), 0, stream>>>(G2);
    }
}

// Round 13
// 154.796 us; speedup vs baseline: 1.0610x; 1.0024x over previous
//
#include <hip/hip_runtime.h>

#define NN 4096
#define NE 8192
#define NLG 32768
#define CAP 32

typedef unsigned int u32;
typedef unsigned short u16;
typedef __attribute__((ext_vector_type(4))) float f32x4;
typedef __attribute__((ext_vector_type(8))) short bf16x8;
typedef __attribute__((ext_vector_type(8))) unsigned short u16x8;
typedef __attribute__((ext_vector_type(4))) unsigned short u16x4;

__device__ __forceinline__ float bf2f(u16 u) { return __uint_as_float(((u32)u) << 16); }
__device__ __forceinline__ u16 f2bf(float f) {
    u32 x = __float_as_uint(f);
    return (u16)((x + 0x7fffu + ((x >> 16) & 1u)) >> 16);  // RNE
}

// ================= K1: prep (converts/transposes/bias) + bucket append, fused =================
struct PAArgs {
    const float *x, *ex;
    const float *nW0, *nW1, *eWl0, *eWu0, *eWl1, *eWu1, *fnW, *feW, *nb0, *nb1;
    const int *nei, *eil, *eiu;
    u32 *cntA, *cntL, *cntU;            // raw counters (zeroed by memset)
    u32 *colA, *colL, *colU, *eidL, *eidU;
    u16 *Zb1n, *Zb1e, *nW0T, *nW1T, *eW1T, *eW2T, *fnWT, *feWT;
    float *nb0s, *nb1s;
};

// Flipped 4-wide transpose: thread reads 4 scattered f32 (stride Nw), stores ONE
// contiguous u16x4 down dst's fast kk dim (kills 2B partial-sector RMW stores).
__device__ __forceinline__ void wtrK4(const float* src, u16* dst, u32 i, int Kp, int Nw, int ld, int kofs) {
    int q = Kp >> 2;
    int nn = i / q, kk = (i - nn * q) * 4;
    u16x4 o;
#pragma unroll
    for (int e = 0; e < 4; ++e) o[e] = f2bf(src[(size_t)(kk + e) * Nw + nn]);
    *(u16x4*)(dst + (size_t)nn * ld + kofs + kk) = o;
}
__device__ __forceinline__ void wtrS4(const float* sa, const float* sb, u16* dst, u32 i, int Kp, int Nw, int ld) {
    int q = Kp >> 2;
    int nn = i / q, kk = (i - nn * q) * 4;
    u16x4 o;
#pragma unroll
    for (int e = 0; e < 4; ++e) o[e] = f2bf(sa[(size_t)(kk + e) * Nw + nn] + sb[(size_t)(kk + e) * Nw + nn]);
    *(u16x4*)(dst + (size_t)nn * ld + kk) = o;
}

__global__ __launch_bounds__(256) void prep_append(PAArgs A) {
    const u32 gid = blockIdx.x * blockDim.x + threadIdx.x;
    const u32 gsz = gridDim.x * blockDim.x;
    const u32 C0 = 32768;                 // x conv (8-col items)
    const u32 C1 = C0 + 32768;            // ex conv (8-col items)
    const u32 C2 = C1 + 6144;             // nW0T (Kp=192, /4)
    const u32 C3 = C2 + 12288;            // nW1T (Kp=384, /4)
    const u32 C4 = C3 + 1024;             // eW1T sum block (Kp=32, /4)
    const u32 C5 = C4 + 1024;             // eWl0 k=1
    const u32 C6 = C5 + 1024;             // eWl0 k=2
    const u32 C7 = C6 + 1024;             // eWu0 k=1
    const u32 C8 = C7 + 1024;             // eWu0 k=2
    const u32 C9 = C8 + 4096;             // eW2T sum block (Kp=128, /4)
    const u32 C10 = C9 + 4096;            // eWl1 k=1
    const u32 C11 = C10 + 4096;           // eWl1 k=2
    const u32 C12 = C11 + 4096;           // eWu1 k=1
    const u32 C13 = C12 + 4096;           // eWu1 k=2
    const u32 C14 = C13 + 2048;           // fnWT
    const u32 C15 = C14 + 2048;           // feWT
    const u32 C16 = C15 + 256;            // bias sums
    const u32 C17 = C16 + (NE + 2 * NLG); // append
    for (u32 i = gid; i < C17; i += gsz) {
        if (i < C0) {
            u32 t = i; int r = t >> 3, c8 = t & 7;
            f32x4 v0 = *(const f32x4*)(A.x + (size_t)t * 8);
            f32x4 v1 = *(const f32x4*)(A.x + (size_t)t * 8 + 4);
            u16x8 o;
#pragma unroll
            for (int e = 0; e < 4; ++e) { o[e] = f2bf(v0[e]); o[4 + e] = f2bf(v1[e]); }
            *(u16x8*)(A.Zb1n + (size_t)r * 192 + c8 * 8) = o;
        } else if (i < C1) {
            u32 t = i - C0; int r = t >> 2, c8 = t & 3;
            f32x4 v0 = *(const f32x4*)(A.ex + (size_t)t * 8);
            f32x4 v1 = *(const f32x4*)(A.ex + (size_t)t * 8 + 4);
            u16x8 o;
#pragma unroll
            for (int e = 0; e < 4; ++e) { o[e] = f2bf(v0[e]); o[4 + e] = f2bf(v1[e]); }
            *(u16x8*)(A.Zb1e + (size_t)r * 160 + c8 * 8) = o;
        }
        else if (i < C2)  wtrK4(A.nW0, A.nW0T, i - C1, 192, 128, 192, 0);
        else if (i < C3)  wtrK4(A.nW1, A.nW1T, i - C2, 384, 128, 384, 0);
        else if (i < C4)  wtrS4(A.eWl0, A.eWu0, A.eW1T, i - C3, 32, 128, 160);
        else if (i < C5)  wtrK4(A.eWl0 + 32 * 128,     A.eW1T, i - C4, 32, 128, 160, 32);
        else if (i < C6)  wtrK4(A.eWl0 + 2 * 32 * 128, A.eW1T, i - C5, 32, 128, 160, 64);
        else if (i < C7)  wtrK4(A.eWu0 + 32 * 128,     A.eW1T, i - C6, 32, 128, 160, 96);
        else if (i < C8)  wtrK4(A.eWu0 + 2 * 32 * 128, A.eW1T, i - C7, 32, 128, 160, 128);
        else if (i < C9)  wtrS4(A.eWl1, A.eWu1, A.eW2T, i - C8, 128, 128, 640);
        else if (i < C10) wtrK4(A.eWl1 + 128 * 128,     A.eW2T, i - C9, 128, 128, 640, 128);
        else if (i < C11) wtrK4(A.eWl1 + 2 * 128 * 128, A.eW2T, i - C10, 128, 128, 640, 256);
        else if (i < C12) wtrK4(A.eWu1 + 128 * 128,     A.eW2T, i - C11, 128, 128, 640, 384);
        else if (i < C13) wtrK4(A.eWu1 + 2 * 128 * 128, A.eW2T, i - C12, 128, 128, 640, 512);
        else if (i < C14) wtrK4(A.fnW, A.fnWT, i - C13, 128, 64, 128, 0);
        else if (i < C15) wtrK4(A.feW, A.feWT, i - C14, 128, 64, 128, 0);
        else if (i < C16) {
            u32 t = i - C15;
            if (t < 128) { float s = 0.f; for (int k = 0; k < 3; ++k) s += A.nb0[k * 128 + t]; A.nb0s[t] = s; }
            else { t -= 128; float s = 0.f; for (int k = 0; k < 3; ++k) s += A.nb1[k * 128 + t]; A.nb1s[t] = s; }
        } else {
            u32 t = i - C16;
            if (t < NE) {
                int r = A.nei[t];
                u32 p = atomicAdd(&A.cntA[r], 1u);
                if (p < CAP) A.colA[r * CAP + p] = (u32)A.nei[NE + t];
            } else if (t < NE + NLG) {
                u32 e = t - NE;
                int r = A.eil[e];
                u32 p = atomicAdd(&A.cntL[r], 1u);
                if (p < CAP) { A.colL[r * CAP + p] = (u32)A.eil[NLG + e]; A.eidL[r * CAP + p] = e; }
            } else {
                u32 e = t - NE - NLG;
                int r = A.eiu[e];
                u32 p = atomicAdd(&A.cntU[r], 1u);
                if (p < CAP) { A.colU[r * CAP + p] = (u32)A.eiu[NLG + e]; A.eidU[r * CAP + p] = e; }
            }
        }
    }
}

// ================= K2: fused resolve + layer-1 hop-1 spmm =================
// Uniform 32-row blocks: A 128 + L 256 + U 256 = 640 blocks, 8 slot-threads/row.
// Phase A resolves into LDS only; rb1 then written COALESCED (full CAP panel;
// slots >= jn are garbage but never read). A: first-slot-wins. L/U: max-eid-wins.
struct RHArgs {
    const u32 *cntA, *cntL, *cntU;
    const u32 *colA, *colL, *colU, *eidL, *eidU;
    const float *eal, *eau;
    uint2 *rb1A, *rb1L, *rb1U;
    u16 *Zb1n, *Zb1e;
};

__global__ __launch_bounds__(256) void resolve_hop1(RHArgs A) {
    __shared__ uint2 bkt[32][33];   // +1 pad: breaks 256B-stride bank aliasing
    __shared__ u32 jns[32];
    const int b = blockIdx.x, tid = threadIdx.x;
    const int seg = (b < 128) ? 0 : (b < 384 ? 1 : 2);   // A / L / U
    const int rowbase = (seg == 0 ? b : (seg == 1 ? b - 128 : b - 384)) * 32;
    const u32* cnt = seg == 0 ? A.cntA : (seg == 1 ? A.cntL : A.cntU);
    const u32* col = seg == 0 ? A.colA : (seg == 1 ? A.colL : A.colU);
    uint2* rb = seg == 0 ? A.rb1A : (seg == 1 ? A.rb1L : A.rb1U);

    // ---- phase A: resolve into LDS (8 slot-threads/row) ----
    {
        const int lr = tid >> 3, s = tid & 7;
        const int row = rowbase + lr;
        u32 jn = cnt[row]; if (jn > CAP) jn = CAP;
        if (s == 0) jns[lr] = jn;
        const u32* cp = col + row * CAP;
        if (seg == 0) {
            for (u32 j = s; j < jn; j += 8) {
                u32 cj = cp[j];
                float w = 1.0f;
                for (u32 j2 = 0; j2 < j; ++j2) if (cp[j2] == cj) { w = 0.0f; break; }
                bkt[lr][j] = make_uint2(cj, __float_as_uint(w));
            }
        } else {
            const u32* ep = (seg == 1 ? A.eidL : A.eidU) + row * CAP;
            const float* wsr = seg == 1 ? A.eal : A.eau;
            for (u32 j = s; j < jn; j += 8) {
                u32 cj = cp[j], ej = ep[j];
                float w = wsr[ej];
                for (u32 j2 = 0; j2 < jn; ++j2)
                    if (j2 != j && cp[j2] == cj && ep[j2] > ej) { w = 0.0f; break; }
                bkt[lr][j] = make_uint2(cj, __float_as_uint(w));
            }
        }
    }
    __syncthreads();

    // ---- coalesced rb1 write (full 32-row panel; >=jn slots unread garbage) ----
    {
        uint2* rbb = rb + (size_t)rowbase * CAP;
        for (int idx = tid; idx < 32 * CAP; idx += 256)
            rbb[idx] = bkt[idx >> 5][idx & 31];
    }

    // ---- phase B: hop-1 gather using LDS buckets (8 col-groups/row) ----
    const int lr2 = tid >> 3, g = tid & 7;
    const int row2 = rowbase + lr2;
    const u32 jn2 = jns[lr2];
    if (seg == 0) {
        // node: 64 cols = 8 groups x 8
        const u16* srcg = A.Zb1n + g * 8;
        float acc[8] = {};
        for (u32 j = 0; j < jn2; ++j) {
            uint2 q = bkt[lr2][j];
            u16x8 xv = *(const u16x8*)(srcg + (size_t)q.x * 192);
            float w = __uint_as_float(q.y);
#pragma unroll
            for (int e = 0; e < 8; ++e) acc[e] = fmaf(w, bf2f(xv[e]), acc[e]);
        }
        u16x8 o;
#pragma unroll
        for (int e = 0; e < 8; ++e) o[e] = f2bf(acc[e]);
        *(u16x8*)(A.Zb1n + 64 + (size_t)row2 * 192 + g * 8) = o;
    } else {
        // edge: 32 cols = 8 groups x 4
        const u16* srcg = A.Zb1e + g * 4;
        u16* dst = seg == 1 ? A.Zb1e + 32 : A.Zb1e + 96;
        float acc[4] = {};
        for (u32 j = 0; j < jn2; ++j) {
            uint2 q = bkt[lr2][j];
            u16x4 xv = *(const u16x4*)(srcg + (size_t)q.x * 160);
            float w = __uint_as_float(q.y);
#pragma unroll
            for (int e = 0; e < 4; ++e) acc[e] = fmaf(w, bf2f(xv[e]), acc[e]);
        }
        u16x4 o;
#pragma unroll
        for (int e = 0; e < 4; ++e) o[e] = f2bf(acc[e]);
        *(u16x4*)(dst + (size_t)row2 * 160 + g * 4) = o;
    }
}

// ================= layer-2 hop-1 spmm: 32-row blocks, LDS-staged buckets =================
struct SPArgs {
    const u32 *cntA, *cntL, *cntU;
    const uint2 *rb1A, *rb1L, *rb1U;
    const u16 *Zb2n, *Zb2e;
    u16 *dn, *dl, *du;                    // dst base ptrs (Zb2n+128, Zb2e+128, Zb2e+384)
};

__global__ __launch_bounds__(256) void spmm16_kernel(SPArgs A) {
    __shared__ uint2 bkt[32][33];
    __shared__ u32 jns[32];
    const int b = blockIdx.x, tid = threadIdx.x;
    const int seg = (b < 128) ? 0 : (b < 384 ? 1 : 2);   // node / L / U
    const int rowbase = (seg == 0 ? b : (seg == 1 ? b - 128 : b - 384)) * 32;
    const u32* cnt = seg == 0 ? A.cntA : (seg == 1 ? A.cntL : A.cntU);
    const uint2* rb = seg == 0 ? A.rb1A : (seg == 1 ? A.rb1L : A.rb1U);
    const u16* src = seg == 0 ? A.Zb2n : A.Zb2e;
    u16* dst = seg == 0 ? A.dn : (seg == 1 ? A.dl : A.du);
    const int ld = seg == 0 ? 384 : 640;

    const int lr = tid >> 3, s = tid & 7;
    const int row = rowbase + lr;
    u32 jn = cnt[row]; if (jn > CAP) jn = CAP;
    if (s == 0) jns[lr] = jn;
    {   // cooperative bucket load, uint4 pairs (2 slots per 16B read)
        const uint4* bp = (const uint4*)(rb + (size_t)row * CAP);
        for (u32 k = s; k * 2 < jn; k += 8) {
            uint4 v = bp[k];
            bkt[lr][2 * k]     = make_uint2(v.x, v.y);
            bkt[lr][2 * k + 1] = make_uint2(v.z, v.w);
        }
    }
    __syncthreads();

    const u32 jn2 = jns[lr];
    const u16* s0 = src + s * 8;
    const u16* s1 = src + s * 8 + 64;
    float acc[16] = {};
    for (u32 j = 0; j < jn2; ++j) {
        uint2 q = bkt[lr][j];
        u16x8 a0 = *(const u16x8*)(s0 + (size_t)q.x * ld);
        u16x8 b0 = *(const u16x8*)(s1 + (size_t)q.x * ld);
        float w = __uint_as_float(q.y);
#pragma unroll
        for (int e = 0; e < 8; ++e) {
            acc[e]     = fmaf(w, bf2f(a0[e]), acc[e]);
            acc[8 + e] = fmaf(w, bf2f(b0[e]), acc[8 + e]);
        }
    }
    u16x8 o0, o1;
#pragma unroll
    for (int e = 0; e < 8; ++e) { o0[e] = f2bf(acc[e]); o1[e] = f2bf(acc[8 + e]); }
    *(u16x8*)(dst + (size_t)row * ld + s * 8) = o0;
    *(u16x8*)(dst + (size_t)row * ld + s * 8 + 64) = o1;
}

// ================= K4: layer-1 GEMM with fused hop-2 =================
// 1 tile/block (grid 768, striped node/edge), 4 waves x 32 N-cols.
// Buckets loaded to LDS via uint4 pairs; 256 threads stage hop-2 (16 thr/row,
// u16x4 slices) from LDS buckets; barrier AFTER global-K MFMA.
struct G1Args {
    const u16 *Zb1n, *Zb1e, *nW0T, *eW1T;
    const float *nb0s, *eb0;
    const u32 *cntA, *cntL, *cntU;
    const uint2 *rb1A, *rb1L, *rb1U;
    u16 *Zb2n, *Zb2e;
};

__global__ __launch_bounds__(256) void gemm1_kernel(G1Args A) {
    __shared__ u16 h2[16][72];        // stride 72: fragment reads land 2-way (free)
    __shared__ uint2 bkt2[2][16][32]; // [A|L][row][slot], [U][row][slot]
    const int tid = threadIdx.x;
    const int wv = tid >> 6, lane = tid & 63;
    const int bid = blockIdx.x;
    const int s = (bid % 3) * 256 + bid / 3;   // stripe: mix node/edge through launch order
    const bool node = s < 256;
    const int m0 = (node ? s : s - 256) * 16;

    // ---- cooperative bucket load (16 thr/row, uint4 pairs) ----
    {
        const int lr = tid >> 4, g = tid & 15;
        const int row = m0 + lr;
        if (node) {
            u32 jn = A.cntA[row]; if (jn > CAP) jn = CAP;
            const uint4* bp = (const uint4*)(A.rb1A + (size_t)row * CAP);
            if ((u32)(2 * g) < jn) {
                uint4 v = bp[g];
                bkt2[0][lr][2 * g]     = make_uint2(v.x, v.y);
                bkt2[0][lr][2 * g + 1] = make_uint2(v.z, v.w);
            }
        } else {
            const int mat = g >> 3, gg = g & 7;     // 8 thr for L, 8 for U (2 uint4 each)
            const u32* cnt = mat == 0 ? A.cntL : A.cntU;
            const uint2* rb = mat == 0 ? A.rb1L : A.rb1U;
            u32 jn = cnt[row]; if (jn > CAP) jn = CAP;
            const uint4* bp = (const uint4*)(rb + (size_t)row * CAP);
            for (u32 k = gg; k * 2 < jn; k += 8) {
                uint4 v = bp[k];
                bkt2[mat][lr][2 * k]     = make_uint2(v.x, v.y);
                bkt2[mat][lr][2 * k + 1] = make_uint2(v.z, v.w);
            }
        }
    }
    __syncthreads();

    // ---- stage hop2 (256 threads, 16 thr/row, 4-col slices) from LDS buckets ----
    {
        const int lr = tid >> 4, g = tid & 15;
        const u32* cnt; const u16* src; int ld, dc, mat;
        if (node) { cnt = A.cntA; src = A.Zb1n + 64 + g * 4; ld = 192; dc = g * 4; mat = 0; }
        else {
            const bool isL = g < 8; const int gg = isL ? g : g - 8;
            cnt = isL ? A.cntL : A.cntU; mat = isL ? 0 : 1;
            src = (isL ? A.Zb1e + 32 : A.Zb1e + 96) + gg * 4; ld = 160;
            dc = (isL ? 0 : 32) + gg * 4;
        }
        const int row = m0 + lr;
        u32 jn = cnt[row]; if (jn > CAP) jn = CAP;
        float acc[4] = {};
        for (u32 j = 0; j < jn; ++j) {
            uint2 qe = bkt2[mat][lr][j];
            float w = __uint_as_float(qe.y);
            u16x4 a0 = *(const u16x4*)(src + (size_t)qe.x * ld);
#pragma unroll
            for (int e = 0; e < 4; ++e) acc[e] = fmaf(w, bf2f(a0[e]), acc[e]);
        }
        u16x4 o0;
#pragma unroll
        for (int e = 0; e < 4; ++e) o0[e] = f2bf(acc[e]);
        *(u16x4*)&h2[lr][dc] = o0;
    }

    // ---- MFMA GEMM, split-K; wave = 32 N-cols; barrier after global-K ----
    const int c = lane & 15, koff = (lane >> 4) * 8;
    const int n0 = wv * 32;
    f32x4 acc[2] = {};
    const u16* Lr = &h2[c][koff];
    if (node) {
        const u16* Ap = A.Zb1n + (size_t)(m0 + c) * 192 + koff;
        const u16* Wp = A.nW0T + (size_t)(n0 + c) * 192 + koff;
        const size_t ws = (size_t)16 * 192;
#pragma unroll
        for (int k0 = 0; k0 < 128; k0 += 32) {
            bf16x8 af = *(const bf16x8*)(Ap + k0);
#pragma unroll
            for (int nt = 0; nt < 2; ++nt)
                acc[nt] = __builtin_amdgcn_mfma_f32_16x16x32_bf16(af, *(const bf16x8*)(Wp + nt * ws + k0), acc[nt], 0, 0, 0);
        }
        __syncthreads();
#pragma unroll
        for (int k0 = 128; k0 < 192; k0 += 32) {
            bf16x8 af = *(const bf16x8*)(Lr + (k0 - 128));
#pragma unroll
            for (int nt = 0; nt < 2; ++nt)
                acc[nt] = __builtin_amdgcn_mfma_f32_16x16x32_bf16(af, *(const bf16x8*)(Wp + nt * ws + k0), acc[nt], 0, 0, 0);
        }
        const int orow = m0 + (lane >> 4) * 4;
#pragma unroll
        for (int nt = 0; nt < 2; ++nt) {
            int col = n0 + nt * 16 + c;
            float bv = A.nb0s[col];
#pragma unroll
            for (int r = 0; r < 4; ++r)
                A.Zb2n[(size_t)(orow + r) * 384 + col] = f2bf(fmaxf(acc[nt][r] + bv, 0.f));
        }
    } else {
        const u16* Ap = A.Zb1e + (size_t)(m0 + c) * 160 + koff;
        const u16* Wp = A.eW1T + (size_t)(n0 + c) * 160 + koff;
        const size_t ws = (size_t)16 * 160;
        bf16x8 af;
        af = *(const bf16x8*)(Ap + 0);
#pragma unroll
        for (int nt = 0; nt < 2; ++nt)
            acc[nt] = __builtin_amdgcn_mfma_f32_16x16x32_bf16(af, *(const bf16x8*)(Wp + nt * ws + 0), acc[nt], 0, 0, 0);
        af = *(const bf16x8*)(Ap + 32);
#pragma unroll
        for (int nt = 0; nt < 2; ++nt)
            acc[nt] = __builtin_amdgcn_mfma_f32_16x16x32_bf16(af, *(const bf16x8*)(Wp + nt * ws + 32), acc[nt], 0, 0, 0);
        af = *(const bf16x8*)(Ap + 96);
#pragma unroll
        for (int nt = 0; nt < 2; ++nt)
            acc[nt] = __builtin_amdgcn_mfma_f32_16x16x32_bf16(af, *(const bf16x8*)(Wp + nt * ws + 96), acc[nt], 0, 0, 0);
        __syncthreads();
        af = *(const bf16x8*)(Lr + 0);      // L2 hop2, kabs 64
#pragma unroll
        for (int nt = 0; nt < 2; ++nt)
            acc[nt] = __builtin_amdgcn_mfma_f32_16x16x32_bf16(af, *(const bf16x8*)(Wp + nt * ws + 64), acc[nt], 0, 0, 0);
        af = *(const bf16x8*)(Lr + 32);     // U2 hop2, kabs 128
#pragma unroll
        for (int nt = 0; nt < 2; ++nt)
            acc[nt] = __builtin_amdgcn_mfma_f32_16x16x32_bf16(af, *(const bf16x8*)(Wp + nt * ws + 128), acc[nt], 0, 0, 0);
        const int orow = m0 + (lane >> 4) * 4;
#pragma unroll
        for (int nt = 0; nt < 2; ++nt) {
            int col = n0 + nt * 16 + c;
            float bv = A.eb0[col];
#pragma unroll
            for (int r = 0; r < 4; ++r)
                A.Zb2e[(size_t)(orow + r) * 640 + col] = f2bf(fmaxf(acc[nt][r] + bv, 0.f));
        }
    }
}

// ================= K6: layer-2 GEMM + head with fused hop-2 =================
// 1 tile/block (grid 768, striped), 8 waves x 16 N-cols (512 thr). Buckets loaded
// to LDS via uint4 pairs; 512 threads stage hop-2 (32 thr/row) from LDS.
// Barrier after global-K. g2 padded to 136 (head reads 2-way).
struct G2Args {
    const u16 *Zb2n, *Zb2e, *nW1T, *eW2T, *fnWT, *feWT;
    const float *nb1s, *eb1, *fnb, *feb;
    const u32 *cntA, *cntL, *cntU;
    const uint2 *rb1A, *rb1L, *rb1U;
    float *outn, *oute;
};

__global__ __launch_bounds__(512) void gemm2_head(G2Args A) {
    __shared__ u16 h2[16][264];       // stride 264: fragment reads land 2-way
    __shared__ u16 g2[16][136];       // +8 pad: head reads 2-way instead of 16-way
    __shared__ uint2 bkt2[2][16][32]; // [A|L][row][slot], [U][row][slot]
    const int tid = threadIdx.x;
    const int wv = tid >> 6, lane = tid & 63;
    const int bid = blockIdx.x;
    const int s = (bid % 3) * 256 + bid / 3;   // stripe: mix node/edge through launch order
    const bool node = s < 256;
    const int m0 = (node ? s : s - 256) * 16;

    // ---- cooperative bucket load (32 thr/row, uint4 pairs) ----
    {
        const int lr = tid >> 5, g = tid & 31;
        const int row = m0 + lr;
        if (node) {
            if (g < 16) {
                u32 jn = A.cntA[row]; if (jn > CAP) jn = CAP;
                const uint4* bp = (const uint4*)(A.rb1A + (size_t)row * CAP);
                if ((u32)(2 * g) < jn) {
                    uint4 v = bp[g];
                    bkt2[0][lr][2 * g]     = make_uint2(v.x, v.y);
                    bkt2[0][lr][2 * g + 1] = make_uint2(v.z, v.w);
                }
            }
        } else {
            const int mat = g >> 4, gg = g & 15;     // 16 thr for L, 16 for U (1 uint4 each)
            const u32* cnt = mat == 0 ? A.cntL : A.cntU;
            const uint2* rb = mat == 0 ? A.rb1L : A.rb1U;
            u32 jn = cnt[row]; if (jn > CAP) jn = CAP;
            const uint4* bp = (const uint4*)(rb + (size_t)row * CAP);
            if ((u32)(2 * gg) < jn) {
                uint4 v = bp[gg];
                bkt2[mat][lr][2 * gg]     = make_uint2(v.x, v.y);
                bkt2[mat][lr][2 * gg + 1] = make_uint2(v.z, v.w);
            }
        }
    }
    __syncthreads();

    // ---- stage hop2 (512 threads, 32 thr/row) from LDS buckets ----
    {
        const int lr = tid >> 5, g = tid & 31;
        const int row = m0 + lr;
        if (node) {
            // 128 cols: 32 x 4-col slices
            u32 jn = A.cntA[row]; if (jn > CAP) jn = CAP;
            const u16* src = A.Zb2n + 128 + g * 4;
            float acc[4] = {};
            for (u32 j = 0; j < jn; ++j) {
                uint2 qe = bkt2[0][lr][j];
                float w = __uint_as_float(qe.y);
                u16x4 a0 = *(const u16x4*)(src + (size_t)qe.x * 384);
#pragma unroll
                for (int e = 0; e < 4; ++e) acc[e] = fmaf(w, bf2f(a0[e]), acc[e]);
            }
            u16x4 o0;
#pragma unroll
            for (int e = 0; e < 4; ++e) o0[e] = f2bf(acc[e]);
            *(u16x4*)&h2[lr][g * 4] = o0;
        } else {
            // 256 cols: g<16 -> L2 slice g (8 cols, dc g*8); g>=16 -> U2 (dc 128+(g-16)*8)
            const bool isL = g < 16; const int gg = isL ? g : g - 16;
            const u32* cnt = isL ? A.cntL : A.cntU;
            const int mat = isL ? 0 : 1;
            const u16* src = (isL ? A.Zb2e + 128 : A.Zb2e + 384) + gg * 8;
            const int dc = (isL ? 0 : 128) + gg * 8;
            u32 jn = cnt[row]; if (jn > CAP) jn = CAP;
            float acc[8] = {};
            for (u32 j = 0; j < jn; ++j) {
                uint2 qe = bkt2[mat][lr][j];
                float w = __uint_as_float(qe.y);
                u16x8 a0 = *(const u16x8*)(src + (size_t)qe.x * 640);
#pragma unroll
                for (int e = 0; e < 8; ++e) acc[e] = fmaf(w, bf2f(a0[e]), acc[e]);
            }
            u16x8 o0;
#pragma unroll
            for (int e = 0; e < 8; ++e) o0[e] = f2bf(acc[e]);
            *(u16x8*)&h2[lr][dc] = o0;
        }
    }

    // ---- layer-2 GEMM: wave wv computes 16 N-cols; barrier after global-K ----
    const int c = lane & 15, q = lane >> 4, koff = q * 8;
    f32x4 acc = {};
    const u16* Lr = &h2[c][koff];
    const u16* hWT; const float *hB; float* outp;
    if (node) {
        hWT = A.fnWT; hB = A.fnb; outp = A.outn;
        const u16* Ap = A.Zb2n + (size_t)(m0 + c) * 384 + koff;
        const u16* Wp = A.nW1T + (size_t)(wv * 16 + c) * 384 + koff;
#pragma unroll
        for (int k0 = 0; k0 < 256; k0 += 32) {
            bf16x8 af = *(const bf16x8*)(Ap + k0);
            acc = __builtin_amdgcn_mfma_f32_16x16x32_bf16(af, *(const bf16x8*)(Wp + k0), acc, 0, 0, 0);
        }
        __syncthreads();
#pragma unroll
        for (int k0 = 256; k0 < 384; k0 += 32) {
            bf16x8 af = *(const bf16x8*)(Lr + (k0 - 256));
            acc = __builtin_amdgcn_mfma_f32_16x16x32_bf16(af, *(const bf16x8*)(Wp + k0), acc, 0, 0, 0);
        }
        {
            int col = wv * 16 + c;
            float bv = A.nb1s[col];
#pragma unroll
            for (int r = 0; r < 4; ++r)
                g2[q * 4 + r][col] = f2bf(fmaxf(acc[r] + bv, 0.f));
        }
    } else {
        hWT = A.feWT; hB = A.feb; outp = A.oute;
        const u16* Ap = A.Zb2e + (size_t)(m0 + c) * 640 + koff;
        const u16* Wp = A.eW2T + (size_t)(wv * 16 + c) * 640 + koff;
#pragma unroll
        for (int k0 = 0; k0 < 256; k0 += 32) {
            bf16x8 af = *(const bf16x8*)(Ap + k0);
            acc = __builtin_amdgcn_mfma_f32_16x16x32_bf16(af, *(const bf16x8*)(Wp + k0), acc, 0, 0, 0);
        }
#pragma unroll
        for (int k0 = 384; k0 < 512; k0 += 32) {
            bf16x8 af = *(const bf16x8*)(Ap + k0);
            acc = __builtin_amdgcn_mfma_f32_16x16x32_bf16(af, *(const bf16x8*)(Wp + k0), acc, 0, 0, 0);
        }
        __syncthreads();
#pragma unroll
        for (int k0 = 256; k0 < 384; k0 += 32) {
            bf16x8 af = *(const bf16x8*)(Lr + (k0 - 256));
            acc = __builtin_amdgcn_mfma_f32_16x16x32_bf16(af, *(const bf16x8*)(Wp + k0), acc, 0, 0, 0);
        }
#pragma unroll
        for (int k0 = 512; k0 < 640; k0 += 32) {
            bf16x8 af = *(const bf16x8*)(Lr + (128 + k0 - 512));
            acc = __builtin_amdgcn_mfma_f32_16x16x32_bf16(af, *(const bf16x8*)(Wp + k0), acc, 0, 0, 0);
        }
        {
            int col = wv * 16 + c;
            float bv = A.eb1[col];
#pragma unroll
            for (int r = 0; r < 4; ++r)
                g2[q * 4 + r][col] = f2bf(fmaxf(acc[r] + bv, 0.f));
        }
    }
    __syncthreads();

    // ---- head: waves 0..3 produce 16 output cols each ----
    if (wv < 4) {
        f32x4 hacc = {};
        const u16* Hp = hWT + (size_t)(wv * 16 + c) * 128 + koff;
#pragma unroll
        for (int k0 = 0; k0 < 128; k0 += 32) {
            bf16x8 af = *(const bf16x8*)(&g2[c][koff + k0]);
            bf16x8 bf = *(const bf16x8*)(Hp + k0);
            hacc = __builtin_amdgcn_mfma_f32_16x16x32_bf16(af, bf, hacc, 0, 0, 0);
        }
        int col = wv * 16 + c;
        float bv = hB[col];
#pragma unroll
        for (int r = 0; r < 4; ++r)
            outp[(size_t)(m0 + q * 4 + r) * 64 + col] = hacc[r] + bv;
    }
}

// ================= launch =================
extern "C" void kernel_launch(void* const* d_in, const int* in_sizes, int n_in,
                              void* d_out, int out_size, void* d_ws, size_t ws_size,
                              hipStream_t stream)
{
    const float* x    = (const float*)d_in[0];
    const float* ex   = (const float*)d_in[1];
    const int*   nei  = (const int*)d_in[2];
    const int*   eil  = (const int*)d_in[3];
    const float* eal  = (const float*)d_in[4];
    const int*   eiu  = (const int*)d_in[5];
    const float* eau  = (const float*)d_in[6];
    const float* nW0  = (const float*)d_in[7];
    const float* nb0  = (const float*)d_in[8];
    const float* nW1  = (const float*)d_in[9];
    const float* nb1  = (const float*)d_in[10];
    const float* fnW  = (const float*)d_in[11];
    const float* fnb  = (const float*)d_in[12];
    const float* eWl0 = (const float*)d_in[13];
    const float* eWu0 = (const float*)d_in[14];
    const float* eb0  = (const float*)d_in[15];
    const float* eWl1 = (const float*)d_in[16];
    const float* eWu1 = (const float*)d_in[17];
    const float* eb1  = (const float*)d_in[18];
    const float* feW  = (const float*)d_in[19];
    const float* feb  = (const float*)d_in[20];

    char* wsb = (char*)d_ws;
    size_t off = 0;
    auto alloc = [&](size_t bytes) { void* p = wsb + off; off += (bytes + 255) & ~(size_t)255; return p; };

    // ---- zeroed region (single small memset): raw append counters only ----
    u32* cntA = (u32*)alloc(NN * 4);
    u32* cntL = (u32*)alloc(NE * 4);
    u32* cntU = (u32*)alloc(NE * 4);
    size_t zbytes = off;   // ~82 KB

    uint2* rb1A = (uint2*)alloc((size_t)NN * CAP * 8);
    uint2* rb1L = (uint2*)alloc((size_t)NE * CAP * 8);
    uint2* rb1U = (uint2*)alloc((size_t)NE * CAP * 8);

    u32* colA = (u32*)alloc((size_t)NN * CAP * 4);
    u32* colL = (u32*)alloc((size_t)NE * CAP * 4);
    u32* colU = (u32*)alloc((size_t)NE * CAP * 4);
    u32* eidL = (u32*)alloc((size_t)NE * CAP * 4);
    u32* eidU = (u32*)alloc((size_t)NE * CAP * 4);

    u16* Zb1n = (u16*)alloc((size_t)4096 * 192 * 2);
    u16* Zb1e = (u16*)alloc((size_t)8192 * 160 * 2);
    u16* Zb2n = (u16*)alloc((size_t)4096 * 384 * 2);
    u16* Zb2e = (u16*)alloc((size_t)8192 * 640 * 2);

    u16* nW0T = (u16*)alloc((size_t)128 * 192 * 2);
    u16* nW1T = (u16*)alloc((size_t)128 * 384 * 2);
    u16* eW1T = (u16*)alloc((size_t)128 * 160 * 2);
    u16* eW2T = (u16*)alloc((size_t)128 * 640 * 2);
    u16* fnWT = (u16*)alloc((size_t)64 * 128 * 2);
    u16* feWT = (u16*)alloc((size_t)64 * 128 * 2);
    float* nb0s = (float*)alloc(128 * 4);
    float* nb1s = (float*)alloc(128 * 4);

    // ---- D0: zero counters (~82 KB) ----
    hipMemsetAsync(d_ws, 0, zbytes, stream);

    // ---- D1: prep + append ----
    PAArgs PA{x, ex, nW0, nW1, eWl0, eWu0, eWl1, eWu1, fnW, feW, nb0, nb1,
              nei, eil, eiu,
              cntA, cntL, cntU, colA, colL, colU, eidL, eidU,
              Zb1n, Zb1e, nW0T, nW1T, eW1T, eW2T, fnWT, feWT, nb0s, nb1s};
    prep_append<<<dim3(736), dim3(256), 0, stream>>>(PA);

    // ---- D2: fused resolve + layer-1 hop-1 (640 x 32-row blocks) ----
    RHArgs RH{cntA, cntL, cntU, colA, colL, colU, eidL, eidU, eal, eau,
              rb1A, rb1L, rb1U, Zb1n, Zb1e};
    resolve_hop1<<<dim3(640), dim3(256), 0, stream>>>(RH);

    // ---- D3: layer-1 GEMMs with fused hop-2 (striped tiles, 4 waves) ----
    {
        G1Args G1{Zb1n, Zb1e, nW0T, eW1T, nb0s, eb0,
                  cntA, cntL, cntU, rb1A, rb1L, rb1U, Zb2n, Zb2e};
        gemm1_kernel<<<dim3(768), dim3(256), 0, stream>>>(G1);
    }

    // ---- D4: layer-2 hop-1 (32-row blocks, LDS buckets) ----
    {
        SPArgs SP{cntA, cntL, cntU, rb1A, rb1L, rb1U,
                  Zb2n, Zb2e, Zb2n + 128, Zb2e + 128, Zb2e + 384};
        spmm16_kernel<<<dim3(640), dim3(256), 0, stream>>>(SP);
    }

    // ---- D5: layer-2 GEMM + head with fused hop-2 (striped tiles, 8 waves) ----
    {
        G2Args G2{Zb2n, Zb2e, nW1T, eW2T, fnWT, feWT,
                  nb1s, eb1, fnb, feb,
                  cntA, cntL, cntU, rb1A, rb1L, rb1U,
                  (float*)d_out, (float*)d_out + 262144};
        gemm2_head<<<dim3(768), dim3(512), 0, stream>>>(G2);
    }
}